// Round 9
// baseline (332.798 us; speedup 1.0000x reference)
//
#include <hip/hip_runtime.h>

#define HWPX 4096   // 64*64 pixels

typedef short s8v  __attribute__((ext_vector_type(8)));   // 8 x bf16 (4 VGPR)
typedef float f4v  __attribute__((ext_vector_type(4)));   // 4 x f32  (MFMA C/D)

__device__ inline unsigned short f2bf(float f) {          // RNE f32 -> bf16
    unsigned u = __float_as_uint(f);
    return (unsigned short)((u + 0x7fffu + ((u >> 16) & 1u)) >> 16);
}
__device__ inline float bf2f(unsigned s) {
    return __uint_as_float(s << 16);
}

// async global->LDS, 16B per lane, wave-uniform LDS base + lane*16
#define GLDS16(gsrc, ldst) \
    __builtin_amdgcn_global_load_lds( \
        (const __attribute__((address_space(1))) unsigned int*)(gsrc), \
        (__attribute__((address_space(3))) unsigned int*)(ldst), 16, 0, 0)

// ---------------------------------------------------------------------------
// Transpose+concat+cast: x_in/x_ref [768][4096] f32 -> xcat [4096 px][1536 ch] bf16
// ---------------------------------------------------------------------------
__global__ __launch_bounds__(256)
void tr_cat_k(const float* __restrict__ xa, const float* __restrict__ xb,
              short* __restrict__ xt)
{
    __shared__ __align__(16) short T[64 * 72];
    const int c0 = blockIdx.x * 64, p0 = blockIdx.y * 64, tid = threadIdx.x;
    for (int i = tid; i < 4096; i += 256) {
        int cl = i >> 6, pl = i & 63;
        int c = c0 + cl;
        float v = (c < 768) ? xa[(size_t)c * HWPX + p0 + pl]
                            : xb[(size_t)(c - 768) * HWPX + p0 + pl];
        T[pl * 72 + cl] = (short)f2bf(v);
    }
    __syncthreads();
    for (int i = tid; i < 512; i += 256) {
        int pl = i >> 3, part = i & 7;
        uint4 v = *(const uint4*)&T[pl * 72 + part * 8];
        *(uint4*)&xt[(size_t)(p0 + pl) * 1536 + c0 + part * 8] = v;
    }
}

// ---------------------------------------------------------------------------
// Fused weight fragment-pack for all 5 weights.
// dst[g][s][f][lane][8] bf16; s = cb*9+t; lane: lm=cout, quad=k-part.
// ---------------------------------------------------------------------------
__device__ inline void wpack1(const float* __restrict__ src, short* __restrict__ dst,
                              int i, int Cin, int Cout, int S, int NB)
{
    int e = i & 7, lane = (i >> 3) & 63;
    int lm = lane & 15, quad = lane >> 4;
    int rest = i >> 9;
    int f = rest % NB;
    int s = (rest / NB) % S;
    int g = rest / (NB * S);
    int cout = g * (NB * 16) + f * 16 + lm;
    int cb = s / 9, t = s % 9;
    int ch = cb * 32 + quad * 8 + e;
    dst[i] = (cout < Cout) ? (short)f2bf(src[((size_t)cout * Cin + ch) * 9 + t]) : 0;
}

#define C1 2654208   // w1: 3g*432s*4f*512
#define C2 2985984   // + w2: 3*54*4*512
#define C3 5640192   // + w3: 24*54*4*512
#define C4 6082560   // + w4: 1*432*2*512
#define C5 11390976  // + dw: 12*216*4*512

__global__ __launch_bounds__(256)
void wpack_all_k(const float* __restrict__ s1, const float* __restrict__ s2,
                 const float* __restrict__ s3, const float* __restrict__ s4,
                 const float* __restrict__ s5,
                 short* __restrict__ d1, short* __restrict__ d2,
                 short* __restrict__ d3, short* __restrict__ d4,
                 short* __restrict__ d5)
{
    int i = blockIdx.x * 256 + threadIdx.x;
    if (i < C1)      wpack1(s1, d1, i,      1536, 192,  432, 4);
    else if (i < C2) wpack1(s2, d2, i - C1, 192,  192,  54,  4);
    else if (i < C3) wpack1(s3, d3, i - C2, 192,  1536, 54,  4);
    else if (i < C4) wpack1(s4, d4, i - C3, 1536, 18,   432, 2);
    else if (i < C5) wpack1(s5, d5, i - C4, 768,  768,  216, 4);
}

// ---------------------------------------------------------------------------
// Flipped implicit-GEMM 3x3 conv, MFMA bf16. Block 256 thr = 4 waves.
// M = pixels (4 rows x 64), N = NB*16 couts (fragment-packed weights from
// global, prefetched one tap ahead). LDS: halo 6x66x40 = 31.7 KB.
// ---------------------------------------------------------------------------
template<int NB>
__global__ __launch_bounds__(256, 3)
void convf_k(const short* __restrict__ Xt, int CinStr,
             const short* __restrict__ Wp, int S, int chunks,
             short* __restrict__ Out, int Cstr, int splitStride)
{
    __shared__ __align__(16) short sH[6 * 66 * 40];   // 31.7 KB
    const int tid = threadIdx.x, lane = tid & 63, wv = tid >> 6;
    const int lm = lane & 15, quad = lane >> 4;
    const int r0 = blockIdx.x * 4;            // 4 pixel rows
    const int g  = blockIdx.y;                // cout group of NB*16
    const int cb0 = blockIdx.z * chunks;
    short* out = Out + (size_t)blockIdx.z * splitStride;

    f4v acc[4][NB];
#pragma unroll
    for (int ma = 0; ma < 4; ++ma)
#pragma unroll
        for (int nb = 0; nb < NB; ++nb)
#pragma unroll
            for (int r = 0; r < 4; ++r) acc[ma][nb][r] = 0.f;

    for (int cc = 0; cc < chunks; ++cc) {
        const int cb = cb0 + cc;
        const short* wpB = Wp + ((size_t)(g * S + cb * 9) * NB) * 512 + lane * 8;
        // prefetch tap-0 weight frags (overlaps halo staging + barrier)
        s8v bb[NB];
#pragma unroll
        for (int f = 0; f < NB; ++f)
            bb[f] = *(const s8v*)&wpB[(size_t)f * 512];

        // ---- stage halo: 6 rows x 66 px x 32 ch (zero-padded) ----
        for (int i = tid; i < 1584; i += 256) {
            int slot = i >> 2, part = i & 3;
            int hr = slot / 66, px = slot % 66;
            int gy = r0 - 1 + hr, gx = px - 1;
            uint4 v = {0, 0, 0, 0};
            if (gy >= 0 && gy < 64 && gx >= 0 && gx < 64)
                v = *(const uint4*)&Xt[(size_t)(gy * 64 + gx) * CinStr + cb * 32 + part * 8];
            *(uint4*)&sH[slot * 40 + part * 8] = v;
        }
        __syncthreads();

#pragma unroll
        for (int t = 0; t < 9; ++t) {
            const int ty = t / 3, tx = t % 3;
            // prefetch next tap (t=8 overreads into the next carved region)
            s8v nxt[NB];
#pragma unroll
            for (int f = 0; f < NB; ++f)
                nxt[f] = *(const s8v*)&wpB[(size_t)((t + 1) * NB + f) * 512];
            s8v a[4];
#pragma unroll
            for (int ma = 0; ma < 4; ++ma)
                a[ma] = *(const s8v*)&sH[((wv + ty) * 66 + ma * 16 + lm + tx) * 40 + quad * 8];
#pragma unroll
            for (int ma = 0; ma < 4; ++ma)
#pragma unroll
                for (int nb = 0; nb < NB; ++nb)
                    acc[ma][nb] = __builtin_amdgcn_mfma_f32_16x16x32_bf16(
                        a[ma], bb[nb], acc[ma][nb], 0, 0, 0);
#pragma unroll
            for (int f = 0; f < NB; ++f) bb[f] = nxt[f];
        }
        __syncthreads();
    }

    const int py = (r0 + wv) * 64;
#pragma unroll
    for (int ma = 0; ma < 4; ++ma)
#pragma unroll
        for (int nb = 0; nb < NB; ++nb)
#pragma unroll
            for (int r = 0; r < 4; ++r)
                out[(size_t)(py + ma * 16 + quad * 4 + r) * Cstr
                    + g * (NB * 16) + nb * 16 + lm] = (short)f2bf(acc[ma][nb][r]);
}

// ---------------------------------------------------------------------------
// Sum bf16 K-split partials, optional relu, -> bf16
// ---------------------------------------------------------------------------
__global__ __launch_bounds__(256)
void ep_sumb_k(const short* __restrict__ P, short* __restrict__ outb,
               int nsplit, size_t splitStride, int n8, int relu)
{
    int i = blockIdx.x * 256 + threadIdx.x;
    if (i >= n8) return;
    size_t base = (size_t)i * 8;
    float s[8];
#pragma unroll
    for (int j = 0; j < 8; ++j) s[j] = 0.f;
    for (int sp = 0; sp < nsplit; ++sp) {
        uint4 v = *(const uint4*)&P[sp * splitStride + base];
        s[0] += bf2f(v.x & 0xffffu); s[1] += bf2f(v.x >> 16);
        s[2] += bf2f(v.y & 0xffffu); s[3] += bf2f(v.y >> 16);
        s[4] += bf2f(v.z & 0xffffu); s[5] += bf2f(v.z >> 16);
        s[6] += bf2f(v.w & 0xffffu); s[7] += bf2f(v.w >> 16);
    }
    if (relu) {
#pragma unroll
        for (int j = 0; j < 8; ++j) s[j] = fmaxf(s[j], 0.f);
    }
    uint4 o;
    o.x = f2bf(s[0]) | ((unsigned)f2bf(s[1]) << 16);
    o.y = f2bf(s[2]) | ((unsigned)f2bf(s[3]) << 16);
    o.z = f2bf(s[4]) | ((unsigned)f2bf(s[5]) << 16);
    o.w = f2bf(s[6]) | ((unsigned)f2bf(s[7]) << 16);
    *(uint4*)&outb[base] = o;
}

// conv4 epilogue: partials bf16 [nsplit][4096][32] -> offs f32 [18][4096]
__global__ __launch_bounds__(256)
void ep_offs_k(const short* __restrict__ P, float* __restrict__ offs, int nsplit)
{
    int i = blockIdx.x * 256 + threadIdx.x;
    if (i >= 18 * HWPX) return;
    int m = i >> 12, px = i & 4095;
    float s = 0.f;
    for (int sp = 0; sp < nsplit; ++sp)
        s += bf2f((unsigned short)P[((size_t)sp * HWPX + px) * 32 + m]);
    offs[i] = s;
}

// ---------------------------------------------------------------------------
// Bilinear sampling v2 -> Smp fragment-packed, WAVE-COALESCED writes.
// ---------------------------------------------------------------------------
__global__ __launch_bounds__(256)
void sample_k(const short* __restrict__ xcat, const float* __restrict__ offs,
              short* __restrict__ Smp)
{
    __shared__ int   s_mi[9][16][4];
    __shared__ float s_mw[9][16][4];
    const int tid = threadIdx.x;
    const int p0  = blockIdx.x * 16;
    const int cbq = blockIdx.y * 6;    // 6 of 24 channel-blocks (32ch each)
    const int wv  = tid >> 6, lane = tid & 63;
    const int lmx = lane & 15, qd = lane >> 4;
    const int pg  = p0 >> 6, ma = (p0 >> 4) & 3;

    if (tid < 144) {
        int t = tid / 16, p = tid % 16;
        int pxg = p0 + p;
        int r = pxg >> 6, x = pxg & 63;
        float dy = offs[(size_t)(2 * t)     * HWPX + pxg];
        float dx = offs[(size_t)(2 * t + 1) * HWPX + pxg];
        float py  = (float)(r - 1 + t / 3) + dy;
        float pxf = (float)(x - 1 + t % 3) + dx;
        py  = fminf(fmaxf(py,  -1e6f), 1e6f);
        pxf = fminf(fmaxf(pxf, -1e6f), 1e6f);
        float y0f = floorf(py), x0f = floorf(pxf);
        float wy1 = py - y0f, wx1 = pxf - x0f;
        float wy0 = 1.f - wy1, wx0 = 1.f - wx1;
        bool vy0 = (y0f >=  0.f) && (y0f <= 63.f);
        bool vy1 = (y0f >= -1.f) && (y0f <= 62.f);
        bool vx0 = (x0f >=  0.f) && (x0f <= 63.f);
        bool vx1 = (x0f >= -1.f) && (x0f <= 62.f);
        int y0 = (int)fminf(fmaxf(y0f,       0.f), 63.f);
        int y1 = (int)fminf(fmaxf(y0f + 1.f, 0.f), 63.f);
        int x0 = (int)fminf(fmaxf(x0f,       0.f), 63.f);
        int x1 = (int)fminf(fmaxf(x0f + 1.f, 0.f), 63.f);
        s_mi[t][p][0] = y0 * 64 + x0;  s_mw[t][p][0] = (vy0 && vx0) ? wy0 * wx0 : 0.f;
        s_mi[t][p][1] = y0 * 64 + x1;  s_mw[t][p][1] = (vy0 && vx1) ? wy0 * wx1 : 0.f;
        s_mi[t][p][2] = y1 * 64 + x0;  s_mw[t][p][2] = (vy1 && vx0) ? wy1 * wx0 : 0.f;
        s_mi[t][p][3] = y1 * 64 + x1;  s_mw[t][p][3] = (vy1 && vx1) ? wy1 * wx1 : 0.f;
    }
    __syncthreads();

    for (int j = wv; j < 54; j += 4) {
        const int t = j / 6, cb = cbq + j % 6;
        int   mi[4];
        float mw[4];
#pragma unroll
        for (int c = 0; c < 4; ++c) {
            mi[c] = s_mi[t][lmx][c];
            mw[c] = s_mw[t][lmx][c];
        }
        float a[8];
#pragma unroll
        for (int k = 0; k < 8; ++k) a[k] = 0.f;
#pragma unroll
        for (int c = 0; c < 4; ++c) {
            float wgt = mw[c];
            const short* src = xcat + (size_t)mi[c] * 1536 + 768 + cb * 32 + qd * 8;
            uint4 v = *(const uint4*)src;
            a[0] += wgt * bf2f(v.x & 0xffffu); a[1] += wgt * bf2f(v.x >> 16);
            a[2] += wgt * bf2f(v.y & 0xffffu); a[3] += wgt * bf2f(v.y >> 16);
            a[4] += wgt * bf2f(v.z & 0xffffu); a[5] += wgt * bf2f(v.z >> 16);
            a[6] += wgt * bf2f(v.w & 0xffffu); a[7] += wgt * bf2f(v.w >> 16);
        }
        uint4 o;
        o.x = f2bf(a[0]) | ((unsigned)f2bf(a[1]) << 16);
        o.y = f2bf(a[2]) | ((unsigned)f2bf(a[3]) << 16);
        o.z = f2bf(a[4]) | ((unsigned)f2bf(a[5]) << 16);
        o.w = f2bf(a[6]) | ((unsigned)f2bf(a[7]) << 16);
        size_t addr = ((((size_t)pg * 216 + cb * 9 + t) * 4 + ma) * 64 + lane) * 8;
        *(uint4*)&Smp[addr] = o;
    }
}

// ---------------------------------------------------------------------------
// Deform GEMM v5: v4 pipeline with FULLY STATIC slot indices (6-step unroll,
// lcm of 2 reg-sets x 3 slots) -> all ds_read/ds-dst offsets are compile-time
// immediates (kills rotation VALU), + s_setprio(1) around MFMA clusters
// (3 skewed blocks/CU give the CU scheduler role diversity to arbitrate).
// Schedule per step: stage(s+2); vmcnt(4); barrier; read(s+1 regs)||MFMA(s).
// ---------------------------------------------------------------------------
template<int SLOTN, int SLOTS, int SOFF>
__device__ __forceinline__ void dg_step(const short* srcP, short* sLp,
                                        int stChunk, int aOff, int bOff, int lane,
                                        f4v (&acc)[4][4],
                                        const s8v (&avC)[4], const s8v (&bvC)[4],
                                        s8v (&avN)[4], s8v (&bvN)[4])
{
#pragma unroll
    for (int j = 0; j < 4; ++j)
        GLDS16(srcP + SOFF + j * 512 + lane * 8,
               &sLp[SLOTS * 8192 + stChunk + j * 512]);
    asm volatile("s_waitcnt vmcnt(4)" ::: "memory");
    __builtin_amdgcn_s_barrier();
    __builtin_amdgcn_sched_barrier(0);
#pragma unroll
    for (int f = 0; f < 4; ++f) {
        avN[f] = *(const s8v*)&sLp[SLOTN * 8192 + aOff + f * 512 + lane * 8];
        bvN[f] = *(const s8v*)&sLp[SLOTN * 8192 + bOff + f * 512 + lane * 8];
    }
    __builtin_amdgcn_s_setprio(1);
#pragma unroll
    for (int ma = 0; ma < 4; ++ma)
#pragma unroll
        for (int nb = 0; nb < 4; ++nb)
            acc[ma][nb] = __builtin_amdgcn_mfma_f32_16x16x32_bf16(
                avC[ma], bvC[nb], acc[ma][nb], 0, 0, 0);
    __builtin_amdgcn_s_setprio(0);
}

__global__ __launch_bounds__(256, 3)
void dgemm_k(const short* __restrict__ Ap, const short* __restrict__ Bp,
             short* __restrict__ P)
{
    __shared__ __align__(16) short sL[3 * 8192];   // 3 slots x 16 KB

    const int tid = threadIdx.x, lane = tid & 63, wv = tid >> 6;
    const int lm = lane & 15, quad = lane >> 4;
    const int mg = blockIdx.y * 2 + (wv >> 1);    // 64-cout group 0..11
    const int pg = blockIdx.x * 2 + (wv & 1);     // 64-px group 0..63
    const int s0 = blockIdx.z * 54;

    // staging role: wave wv copies one 4KB chunk per s-step
    const short* stSrc;
    int stChunk;
    if (wv < 2) {
        stSrc = Ap + ((size_t)(blockIdx.y * 2 + wv) * 216 + s0) * 2048;
        stChunk = wv * 2048;
    } else {
        stSrc = Bp + ((size_t)(blockIdx.x * 2 + (wv - 2)) * 216 + s0) * 2048;
        stChunk = 4096 + (wv - 2) * 2048;
    }

    f4v acc[4][4];
#pragma unroll
    for (int ma = 0; ma < 4; ++ma)
#pragma unroll
        for (int nb = 0; nb < 4; ++nb)
#pragma unroll
            for (int r = 0; r < 4; ++r) acc[ma][nb][r] = 0.f;

    // prologue: stage s=0 -> slot0, s=1 -> slot1
#pragma unroll
    for (int j = 0; j < 4; ++j)
        GLDS16(stSrc + (size_t)0 * 2048 + j * 512 + lane * 8,
               &sL[0 * 8192 + stChunk + j * 512]);
#pragma unroll
    for (int j = 0; j < 4; ++j)
        GLDS16(stSrc + (size_t)1 * 2048 + j * 512 + lane * 8,
               &sL[1 * 8192 + stChunk + j * 512]);
    asm volatile("s_waitcnt vmcnt(4)" ::: "memory");   // stage(0) landed (own)
    __builtin_amdgcn_s_barrier();                      // ... by all waves
    __builtin_amdgcn_sched_barrier(0);

    const int aOff = (wv >> 1) * 2048;
    const int bOff = 4096 + (wv & 1) * 2048;

    s8v avA[4], bvA[4], avB[4], bvB[4];
    // read slot0 -> regs A (frags for step 0)
#pragma unroll
    for (int f = 0; f < 4; ++f) {
        avA[f] = *(const s8v*)&sL[0 * 8192 + aOff + f * 512 + lane * 8];
        bvA[f] = *(const s8v*)&sL[0 * 8192 + bOff + f * 512 + lane * 8];
    }

    const short* srcP = stSrc;   // points at current 6-group's step-0 chunk

    for (int g = 0; g < 8; ++g) {  // steps 6g .. 6g+5  (0..47)
        dg_step<1, 2, 2 * 2048>(srcP, sL, stChunk, aOff, bOff, lane, acc, avA, bvA, avB, bvB);
        dg_step<2, 0, 3 * 2048>(srcP, sL, stChunk, aOff, bOff, lane, acc, avB, bvB, avA, bvA);
        dg_step<0, 1, 4 * 2048>(srcP, sL, stChunk, aOff, bOff, lane, acc, avA, bvA, avB, bvB);
        dg_step<1, 2, 5 * 2048>(srcP, sL, stChunk, aOff, bOff, lane, acc, avB, bvB, avA, bvA);
        dg_step<2, 0, 6 * 2048>(srcP, sL, stChunk, aOff, bOff, lane, acc, avA, bvA, avB, bvB);
        dg_step<0, 1, 7 * 2048>(srcP, sL, stChunk, aOff, bOff, lane, acc, avB, bvB, avA, bvA);
        srcP += 6 * 2048;
    }
    // steps 48..51 (srcP at step 48; stages reach step 53)
    dg_step<1, 2, 2 * 2048>(srcP, sL, stChunk, aOff, bOff, lane, acc, avA, bvA, avB, bvB);
    dg_step<2, 0, 3 * 2048>(srcP, sL, stChunk, aOff, bOff, lane, acc, avB, bvB, avA, bvA);
    dg_step<0, 1, 4 * 2048>(srcP, sL, stChunk, aOff, bOff, lane, acc, avA, bvA, avB, bvB);
    dg_step<1, 2, 5 * 2048>(srcP, sL, stChunk, aOff, bOff, lane, acc, avB, bvB, avA, bvA);

    // ---- tail: steps 52 (regs A, already loaded) and 53 (slot 2) ----
    asm volatile("s_waitcnt vmcnt(0)" ::: "memory");       // stage(53) landed
    __builtin_amdgcn_s_barrier();
    __builtin_amdgcn_sched_barrier(0);
#pragma unroll
    for (int f = 0; f < 4; ++f) {
        avB[f] = *(const s8v*)&sL[2 * 8192 + aOff + f * 512 + lane * 8];
        bvB[f] = *(const s8v*)&sL[2 * 8192 + bOff + f * 512 + lane * 8];
    }
    __builtin_amdgcn_s_setprio(1);
#pragma unroll
    for (int ma = 0; ma < 4; ++ma)
#pragma unroll
        for (int nb = 0; nb < 4; ++nb)
            acc[ma][nb] = __builtin_amdgcn_mfma_f32_16x16x32_bf16(
                avA[ma], bvA[nb], acc[ma][nb], 0, 0, 0);
#pragma unroll
    for (int ma = 0; ma < 4; ++ma)
#pragma unroll
        for (int nb = 0; nb < 4; ++nb)
            acc[ma][nb] = __builtin_amdgcn_mfma_f32_16x16x32_bf16(
                avB[ma], bvB[nb], acc[ma][nb], 0, 0, 0);
    __builtin_amdgcn_s_setprio(0);

    short* p = P + (size_t)blockIdx.z * 768 * HWPX;
#pragma unroll
    for (int ma = 0; ma < 4; ++ma)
#pragma unroll
        for (int nb = 0; nb < 4; ++nb)
#pragma unroll
            for (int r = 0; r < 4; ++r)
                p[(size_t)(mg * 64 + ma * 16 + quad * 4 + r) * HWPX
                  + pg * 64 + nb * 16 + lm] = (short)f2bf(acc[ma][nb][r]);
}

// out f32 = sum of 4 bf16 partials
__global__ __launch_bounds__(256)
void ep_dg_k(const short* __restrict__ P, float* __restrict__ out)
{
    int i = blockIdx.x * 256 + threadIdx.x;
    if (i >= 768 * HWPX / 8) return;
    size_t base = (size_t)i * 8;
    float s[8];
#pragma unroll
    for (int j = 0; j < 8; ++j) s[j] = 0.f;
    for (int sp = 0; sp < 4; ++sp) {
        uint4 v = *(const uint4*)&P[(size_t)sp * 768 * HWPX + base];
        s[0] += bf2f(v.x & 0xffffu); s[1] += bf2f(v.x >> 16);
        s[2] += bf2f(v.y & 0xffffu); s[3] += bf2f(v.y >> 16);
        s[4] += bf2f(v.z & 0xffffu); s[5] += bf2f(v.z >> 16);
        s[6] += bf2f(v.w & 0xffffu); s[7] += bf2f(v.w >> 16);
    }
    float4 o0 = make_float4(s[0], s[1], s[2], s[3]);
    float4 o1 = make_float4(s[4], s[5], s[6], s[7]);
    *(float4*)&out[base]     = o0;
    *(float4*)&out[base + 4] = o1;
}

// ---------------------------------------------------------------------------
extern "C" void kernel_launch(void* const* d_in, const int* in_sizes, int n_in,
                              void* d_out, int out_size, void* d_ws, size_t ws_size,
                              hipStream_t stream)
{
    const float* x_in  = (const float*)d_in[0];
    const float* x_ref = (const float*)d_in[1];
    const float* w1    = (const float*)d_in[2];
    const float* w2    = (const float*)d_in[3];
    const float* w3    = (const float*)d_in[4];
    const float* ow    = (const float*)d_in[5];
    const float* dw    = (const float*)d_in[6];
    float* out = (float*)d_out;

    char* w = (char*)d_ws;
    size_t off = 0;
    auto carve = [&](size_t bytes) {
        void* p = w + off;
        off += (bytes + 255) & ~(size_t)255;
        return p;
    };
    short* xcat = (short*)carve((size_t)4096 * 1536 * 2);        // 12.58 MB
    short* w1p  = (short*)carve((size_t)C1 * 2);                 //  5.31 MB (NB=4)
    short* w2p  = (short*)carve((size_t)(C2 - C1) * 2);          //  0.66 MB (NB=4)
    short* w3p  = (short*)carve((size_t)(C3 - C2) * 2);          //  5.31 MB (NB=4)
    short* w4p  = (short*)carve((size_t)(C4 - C3) * 2);          //  0.88 MB (NB=2)
    short* dwp  = (short*)carve((size_t)(C5 - C4) * 2);          // 10.62 MB (NB=4)
    float* offs = (float*)carve((size_t)18 * 4096 * 4);          //  0.29 MB
    short* Smp  = (short*)carve((size_t)4096 * 6912 * 2);        // 56.62 MB
    // REGION R: 25.17 MB, aliased across phases
    char*  R    = (char*)carve((size_t)2 * 768 * 4096 * 4);
    short* rh1  = (short*)R;                    // [4096][192] bf16
    short* rh2  = (short*)(R + 1572864);        // [4096][192] bf16
    short* est  = (short*)(R + 3145728);        // [4096][1536] bf16
    short* Pcv  = Smp;                          // conv partials (Smp idle til sample)
    short* Pdg  = (short*)R;                    // dgemm partials [4][768][4096] bf16

    tr_cat_k<<<dim3(24, 64), 256, 0, stream>>>(x_in, x_ref, xcat);
    wpack_all_k<<<(C5 + 255) / 256, 256, 0, stream>>>(w1, w2, w3, ow, dw,
                                                      w1p, w2p, w3p, w4p, dwp);

    const int n8 = 4096 * 192 / 8;
    // conv1: 1536->192 relu; N=64, ksplit 16 x 3 chunks; partials in Smp
    convf_k<4><<<dim3(16, 3, 16), 256, 0, stream>>>(xcat, 1536, w1p, 432, 3,
                                                    Pcv, 192, 4096 * 192);
    ep_sumb_k<<<(n8 + 255) / 256, 256, 0, stream>>>(Pcv, rh1, 16, (size_t)4096 * 192, n8, 1);
    // conv2: 192->192 relu; N=64, ksplit 6 x 1 chunk
    convf_k<4><<<dim3(16, 3, 6), 256, 0, stream>>>(rh1, 192, w2p, 54, 1,
                                                   Pcv, 192, 4096 * 192);
    ep_sumb_k<<<(n8 + 255) / 256, 256, 0, stream>>>(Pcv, rh2, 6, (size_t)4096 * 192, n8, 1);
    // conv3: 192->1536; N=64, ksplit 2 x 3 chunks; partials in Smp -> est
    convf_k<4><<<dim3(16, 24, 2), 256, 0, stream>>>(rh2, 192, w3p, 54, 3,
                                                    Pcv, 1536, 4096 * 1536);
    {
        const int n8c3 = 4096 * 1536 / 8;
        ep_sumb_k<<<(n8c3 + 255) / 256, 256, 0, stream>>>(Pcv, est, 2, (size_t)4096 * 1536, n8c3, 0);
    }
    // conv4: 1536->18(pad 32); N=32, ksplit 48 x 1 chunk; partials in Smp
    convf_k<2><<<dim3(16, 1, 48), 256, 0, stream>>>(est, 1536, w4p, 432, 1,
                                                    Pcv, 32, 4096 * 32);
    ep_offs_k<<<(18 * HWPX + 255) / 256, 256, 0, stream>>>(Pcv, offs, 48);
    // deformable conv: coalesced-write sampling, static-pipelined LDS GEMM
    sample_k<<<dim3(256, 4), 256, 0, stream>>>(xcat, offs, Smp);
    dgemm_k<<<dim3(32, 6, 4), 256, 0, stream>>>(dwp, Smp, Pdg);
    ep_dg_k<<<(768 * HWPX / 8 + 255) / 256, 256, 0, stream>>>(Pdg, out);
}

// Round 10
// 329.767 us; speedup vs baseline: 1.0092x; 1.0092x over previous
//
#include <hip/hip_runtime.h>

#define HWPX 4096   // 64*64 pixels

typedef short s8v  __attribute__((ext_vector_type(8)));   // 8 x bf16 (4 VGPR)
typedef float f4v  __attribute__((ext_vector_type(4)));   // 4 x f32  (MFMA C/D)

__device__ inline unsigned short f2bf(float f) {          // RNE f32 -> bf16
    unsigned u = __float_as_uint(f);
    return (unsigned short)((u + 0x7fffu + ((u >> 16) & 1u)) >> 16);
}
__device__ inline float bf2f(unsigned s) {
    return __uint_as_float(s << 16);
}

// async global->LDS, 16B per lane, wave-uniform LDS base + lane*16
#define GLDS16(gsrc, ldst) \
    __builtin_amdgcn_global_load_lds( \
        (const __attribute__((address_space(1))) unsigned int*)(gsrc), \
        (__attribute__((address_space(3))) unsigned int*)(ldst), 16, 0, 0)

// ---------------------------------------------------------------------------
// Transpose+concat+cast: x_in/x_ref [768][4096] f32 -> xcat [4096 px][1536 ch] bf16
// ---------------------------------------------------------------------------
__global__ __launch_bounds__(256)
void tr_cat_k(const float* __restrict__ xa, const float* __restrict__ xb,
              short* __restrict__ xt)
{
    __shared__ __align__(16) short T[64 * 72];
    const int c0 = blockIdx.x * 64, p0 = blockIdx.y * 64, tid = threadIdx.x;
    for (int i = tid; i < 4096; i += 256) {
        int cl = i >> 6, pl = i & 63;
        int c = c0 + cl;
        float v = (c < 768) ? xa[(size_t)c * HWPX + p0 + pl]
                            : xb[(size_t)(c - 768) * HWPX + p0 + pl];
        T[pl * 72 + cl] = (short)f2bf(v);
    }
    __syncthreads();
    for (int i = tid; i < 512; i += 256) {
        int pl = i >> 3, part = i & 7;
        uint4 v = *(const uint4*)&T[pl * 72 + part * 8];
        *(uint4*)&xt[(size_t)(p0 + pl) * 1536 + c0 + part * 8] = v;
    }
}

// ---------------------------------------------------------------------------
// Fused weight fragment-pack for all 5 weights.
// dst[g][s][f][lane][8] bf16; s = cb*9+t; lane: lm=cout, quad=k-part.
// ---------------------------------------------------------------------------
__device__ inline void wpack1(const float* __restrict__ src, short* __restrict__ dst,
                              int i, int Cin, int Cout, int S, int NB)
{
    int e = i & 7, lane = (i >> 3) & 63;
    int lm = lane & 15, quad = lane >> 4;
    int rest = i >> 9;
    int f = rest % NB;
    int s = (rest / NB) % S;
    int g = rest / (NB * S);
    int cout = g * (NB * 16) + f * 16 + lm;
    int cb = s / 9, t = s % 9;
    int ch = cb * 32 + quad * 8 + e;
    dst[i] = (cout < Cout) ? (short)f2bf(src[((size_t)cout * Cin + ch) * 9 + t]) : 0;
}

#define C1 2654208   // w1: 3g*432s*4f*512
#define C2 2985984   // + w2: 6g*54s*2f*512 (NB=2)
#define C3 5640192   // + w3: 24*54*4*512
#define C4 6082560   // + w4: 1*432*2*512
#define C5 11390976  // + dw: 12*216*4*512

__global__ __launch_bounds__(256)
void wpack_all_k(const float* __restrict__ s1, const float* __restrict__ s2,
                 const float* __restrict__ s3, const float* __restrict__ s4,
                 const float* __restrict__ s5,
                 short* __restrict__ d1, short* __restrict__ d2,
                 short* __restrict__ d3, short* __restrict__ d4,
                 short* __restrict__ d5)
{
    int i = blockIdx.x * 256 + threadIdx.x;
    if (i < C1)      wpack1(s1, d1, i,      1536, 192,  432, 4);
    else if (i < C2) wpack1(s2, d2, i - C1, 192,  192,  54,  2);
    else if (i < C3) wpack1(s3, d3, i - C2, 192,  1536, 54,  4);
    else if (i < C4) wpack1(s4, d4, i - C3, 1536, 18,   432, 2);
    else if (i < C5) wpack1(s5, d5, i - C4, 768,  768,  216, 4);
}

// ---------------------------------------------------------------------------
// Flipped implicit-GEMM 3x3 conv, MFMA bf16. Block 256 thr = 4 waves.
// M = pixels (4 rows x 64), N = NB*16 couts (fragment-packed weights from
// global, prefetched one tap ahead). LDS: halo 6x66x40 = 31.7 KB.
// ---------------------------------------------------------------------------
template<int NB>
__global__ __launch_bounds__(256, 3)
void convf_k(const short* __restrict__ Xt, int CinStr,
             const short* __restrict__ Wp, int S, int chunks,
             short* __restrict__ Out, int Cstr, int splitStride)
{
    __shared__ __align__(16) short sH[6 * 66 * 40];   // 31.7 KB
    const int tid = threadIdx.x, lane = tid & 63, wv = tid >> 6;
    const int lm = lane & 15, quad = lane >> 4;
    const int r0 = blockIdx.x * 4;            // 4 pixel rows
    const int g  = blockIdx.y;                // cout group of NB*16
    const int cb0 = blockIdx.z * chunks;
    short* out = Out + (size_t)blockIdx.z * splitStride;

    f4v acc[4][NB];
#pragma unroll
    for (int ma = 0; ma < 4; ++ma)
#pragma unroll
        for (int nb = 0; nb < NB; ++nb)
#pragma unroll
            for (int r = 0; r < 4; ++r) acc[ma][nb][r] = 0.f;

    for (int cc = 0; cc < chunks; ++cc) {
        const int cb = cb0 + cc;
        const short* wpB = Wp + ((size_t)(g * S + cb * 9) * NB) * 512 + lane * 8;
        // prefetch tap-0 weight frags (overlaps halo staging + barrier)
        s8v bb[NB];
#pragma unroll
        for (int f = 0; f < NB; ++f)
            bb[f] = *(const s8v*)&wpB[(size_t)f * 512];

        // ---- stage halo: 6 rows x 66 px x 32 ch (zero-padded) ----
        for (int i = tid; i < 1584; i += 256) {
            int slot = i >> 2, part = i & 3;
            int hr = slot / 66, px = slot % 66;
            int gy = r0 - 1 + hr, gx = px - 1;
            uint4 v = {0, 0, 0, 0};
            if (gy >= 0 && gy < 64 && gx >= 0 && gx < 64)
                v = *(const uint4*)&Xt[(size_t)(gy * 64 + gx) * CinStr + cb * 32 + part * 8];
            *(uint4*)&sH[slot * 40 + part * 8] = v;
        }
        __syncthreads();

#pragma unroll
        for (int t = 0; t < 9; ++t) {
            const int ty = t / 3, tx = t % 3;
            // prefetch next tap (t=8 overreads into the next carved region)
            s8v nxt[NB];
#pragma unroll
            for (int f = 0; f < NB; ++f)
                nxt[f] = *(const s8v*)&wpB[(size_t)((t + 1) * NB + f) * 512];
            s8v a[4];
#pragma unroll
            for (int ma = 0; ma < 4; ++ma)
                a[ma] = *(const s8v*)&sH[((wv + ty) * 66 + ma * 16 + lm + tx) * 40 + quad * 8];
#pragma unroll
            for (int ma = 0; ma < 4; ++ma)
#pragma unroll
                for (int nb = 0; nb < NB; ++nb)
                    acc[ma][nb] = __builtin_amdgcn_mfma_f32_16x16x32_bf16(
                        a[ma], bb[nb], acc[ma][nb], 0, 0, 0);
#pragma unroll
            for (int f = 0; f < NB; ++f) bb[f] = nxt[f];
        }
        __syncthreads();
    }

    const int py = (r0 + wv) * 64;
#pragma unroll
    for (int ma = 0; ma < 4; ++ma)
#pragma unroll
        for (int nb = 0; nb < NB; ++nb)
#pragma unroll
            for (int r = 0; r < 4; ++r)
                out[(size_t)(py + ma * 16 + quad * 4 + r) * Cstr
                    + g * (NB * 16) + nb * 16 + lm] = (short)f2bf(acc[ma][nb][r]);
}

// ---------------------------------------------------------------------------
// Sum bf16 K-split partials, optional relu, -> bf16
// ---------------------------------------------------------------------------
__global__ __launch_bounds__(256)
void ep_sumb_k(const short* __restrict__ P, short* __restrict__ outb,
               int nsplit, size_t splitStride, int n8, int relu)
{
    int i = blockIdx.x * 256 + threadIdx.x;
    if (i >= n8) return;
    size_t base = (size_t)i * 8;
    float s[8];
#pragma unroll
    for (int j = 0; j < 8; ++j) s[j] = 0.f;
    for (int sp = 0; sp < nsplit; ++sp) {
        uint4 v = *(const uint4*)&P[sp * splitStride + base];
        s[0] += bf2f(v.x & 0xffffu); s[1] += bf2f(v.x >> 16);
        s[2] += bf2f(v.y & 0xffffu); s[3] += bf2f(v.y >> 16);
        s[4] += bf2f(v.z & 0xffffu); s[5] += bf2f(v.z >> 16);
        s[6] += bf2f(v.w & 0xffffu); s[7] += bf2f(v.w >> 16);
    }
    if (relu) {
#pragma unroll
        for (int j = 0; j < 8; ++j) s[j] = fmaxf(s[j], 0.f);
    }
    uint4 o;
    o.x = f2bf(s[0]) | ((unsigned)f2bf(s[1]) << 16);
    o.y = f2bf(s[2]) | ((unsigned)f2bf(s[3]) << 16);
    o.z = f2bf(s[4]) | ((unsigned)f2bf(s[5]) << 16);
    o.w = f2bf(s[6]) | ((unsigned)f2bf(s[7]) << 16);
    *(uint4*)&outb[base] = o;
}

// conv4 epilogue: partials bf16 [nsplit][4096][32] -> offs f32 [18][4096]
__global__ __launch_bounds__(256)
void ep_offs_k(const short* __restrict__ P, float* __restrict__ offs, int nsplit)
{
    int i = blockIdx.x * 256 + threadIdx.x;
    if (i >= 18 * HWPX) return;
    int m = i >> 12, px = i & 4095;
    float s = 0.f;
    for (int sp = 0; sp < nsplit; ++sp)
        s += bf2f((unsigned short)P[((size_t)sp * HWPX + px) * 32 + m]);
    offs[i] = s;
}

// ---------------------------------------------------------------------------
// Bilinear sampling v2 -> Smp fragment-packed, WAVE-COALESCED writes.
// ---------------------------------------------------------------------------
__global__ __launch_bounds__(256)
void sample_k(const short* __restrict__ xcat, const float* __restrict__ offs,
              short* __restrict__ Smp)
{
    __shared__ int   s_mi[9][16][4];
    __shared__ float s_mw[9][16][4];
    const int tid = threadIdx.x;
    const int p0  = blockIdx.x * 16;
    const int cbq = blockIdx.y * 6;    // 6 of 24 channel-blocks (32ch each)
    const int wv  = tid >> 6, lane = tid & 63;
    const int lmx = lane & 15, qd = lane >> 4;
    const int pg  = p0 >> 6, ma = (p0 >> 4) & 3;

    if (tid < 144) {
        int t = tid / 16, p = tid % 16;
        int pxg = p0 + p;
        int r = pxg >> 6, x = pxg & 63;
        float dy = offs[(size_t)(2 * t)     * HWPX + pxg];
        float dx = offs[(size_t)(2 * t + 1) * HWPX + pxg];
        float py  = (float)(r - 1 + t / 3) + dy;
        float pxf = (float)(x - 1 + t % 3) + dx;
        py  = fminf(fmaxf(py,  -1e6f), 1e6f);
        pxf = fminf(fmaxf(pxf, -1e6f), 1e6f);
        float y0f = floorf(py), x0f = floorf(pxf);
        float wy1 = py - y0f, wx1 = pxf - x0f;
        float wy0 = 1.f - wy1, wx0 = 1.f - wx1;
        bool vy0 = (y0f >=  0.f) && (y0f <= 63.f);
        bool vy1 = (y0f >= -1.f) && (y0f <= 62.f);
        bool vx0 = (x0f >=  0.f) && (x0f <= 63.f);
        bool vx1 = (x0f >= -1.f) && (x0f <= 62.f);
        int y0 = (int)fminf(fmaxf(y0f,       0.f), 63.f);
        int y1 = (int)fminf(fmaxf(y0f + 1.f, 0.f), 63.f);
        int x0 = (int)fminf(fmaxf(x0f,       0.f), 63.f);
        int x1 = (int)fminf(fmaxf(x0f + 1.f, 0.f), 63.f);
        s_mi[t][p][0] = y0 * 64 + x0;  s_mw[t][p][0] = (vy0 && vx0) ? wy0 * wx0 : 0.f;
        s_mi[t][p][1] = y0 * 64 + x1;  s_mw[t][p][1] = (vy0 && vx1) ? wy0 * wx1 : 0.f;
        s_mi[t][p][2] = y1 * 64 + x0;  s_mw[t][p][2] = (vy1 && vx0) ? wy1 * wx0 : 0.f;
        s_mi[t][p][3] = y1 * 64 + x1;  s_mw[t][p][3] = (vy1 && vx1) ? wy1 * wx1 : 0.f;
    }
    __syncthreads();

    for (int j = wv; j < 54; j += 4) {
        const int t = j / 6, cb = cbq + j % 6;
        int   mi[4];
        float mw[4];
#pragma unroll
        for (int c = 0; c < 4; ++c) {
            mi[c] = s_mi[t][lmx][c];
            mw[c] = s_mw[t][lmx][c];
        }
        float a[8];
#pragma unroll
        for (int k = 0; k < 8; ++k) a[k] = 0.f;
#pragma unroll
        for (int c = 0; c < 4; ++c) {
            float wgt = mw[c];
            const short* src = xcat + (size_t)mi[c] * 1536 + 768 + cb * 32 + qd * 8;
            uint4 v = *(const uint4*)src;
            a[0] += wgt * bf2f(v.x & 0xffffu); a[1] += wgt * bf2f(v.x >> 16);
            a[2] += wgt * bf2f(v.y & 0xffffu); a[3] += wgt * bf2f(v.y >> 16);
            a[4] += wgt * bf2f(v.z & 0xffffu); a[5] += wgt * bf2f(v.z >> 16);
            a[6] += wgt * bf2f(v.w & 0xffffu); a[7] += wgt * bf2f(v.w >> 16);
        }
        uint4 o;
        o.x = f2bf(a[0]) | ((unsigned)f2bf(a[1]) << 16);
        o.y = f2bf(a[2]) | ((unsigned)f2bf(a[3]) << 16);
        o.z = f2bf(a[4]) | ((unsigned)f2bf(a[5]) << 16);
        o.w = f2bf(a[6]) | ((unsigned)f2bf(a[7]) << 16);
        size_t addr = ((((size_t)pg * 216 + cb * 9 + t) * 4 + ma) * 64 + lane) * 8;
        *(uint4*)&Smp[addr] = o;
    }
}

// ---------------------------------------------------------------------------
// Deform GEMM v4 (best verified, R8): LDS staging (3-slot, global_load_lds,
// counted vmcnt) + one-step-ahead LDS->reg prefetch: MFMA(step s) runs on
// registers loaded LAST step while this step's ds_reads fill the DS pipe.
// Unroll x2 with named reg sets A/B; slot rotation (cA,cB,cC)<-(cC,cA,cB).
// ---------------------------------------------------------------------------
__global__ __launch_bounds__(256, 3)
void dgemm_k(const short* __restrict__ Ap, const short* __restrict__ Bp,
             short* __restrict__ P)
{
    __shared__ __align__(16) short sL[3 * 8192];   // 3 slots x 16 KB

    const int tid = threadIdx.x, lane = tid & 63, wv = tid >> 6;
    const int lm = lane & 15, quad = lane >> 4;
    const int mg = blockIdx.y * 2 + (wv >> 1);    // 64-cout group 0..11
    const int pg = blockIdx.x * 2 + (wv & 1);     // 64-px group 0..63
    const int s0 = blockIdx.z * 54;

    // staging role: wave wv copies one 4KB chunk per s-step
    const short* stSrc;
    int stChunk;
    if (wv < 2) {
        stSrc = Ap + ((size_t)(blockIdx.y * 2 + wv) * 216 + s0) * 2048;
        stChunk = wv * 2048;
    } else {
        stSrc = Bp + ((size_t)(blockIdx.x * 2 + (wv - 2)) * 216 + s0) * 2048;
        stChunk = 4096 + (wv - 2) * 2048;
    }

    f4v acc[4][4];
#pragma unroll
    for (int ma = 0; ma < 4; ++ma)
#pragma unroll
        for (int nb = 0; nb < 4; ++nb)
#pragma unroll
            for (int r = 0; r < 4; ++r) acc[ma][nb][r] = 0.f;

    // prologue: stage s=0 -> slot0, s=1 -> slot1
#pragma unroll
    for (int j = 0; j < 4; ++j)
        GLDS16(stSrc + (size_t)0 * 2048 + j * 512 + lane * 8,
               &sL[0 * 8192 + stChunk + j * 512]);
#pragma unroll
    for (int j = 0; j < 4; ++j)
        GLDS16(stSrc + (size_t)1 * 2048 + j * 512 + lane * 8,
               &sL[1 * 8192 + stChunk + j * 512]);
    asm volatile("s_waitcnt vmcnt(4)" ::: "memory");   // stage(0) landed (own)
    __builtin_amdgcn_s_barrier();                      // ... by all waves
    __builtin_amdgcn_sched_barrier(0);

    const int aOff = (wv >> 1) * 2048;
    const int bOff = 4096 + (wv & 1) * 2048;

    s8v avA[4], bvA[4], avB[4], bvB[4];
    // read slot0 -> regs A (frags for step 0)
#pragma unroll
    for (int f = 0; f < 4; ++f) {
        avA[f] = *(const s8v*)&sL[0 * 8192 + aOff + f * 512 + lane * 8];
        bvA[f] = *(const s8v*)&sL[0 * 8192 + bOff + f * 512 + lane * 8];
    }

    int cA = 0, cB = 1, cC = 2;   // slots of steps s, s+1, s+2

    for (int s = 0; s < 52; s += 2) {
        // ---- even: execute step s, read step s+1, stage step s+2 ----
#pragma unroll
        for (int j = 0; j < 4; ++j)
            GLDS16(stSrc + (size_t)(s + 2) * 2048 + j * 512 + lane * 8,
                   &sL[cC * 8192 + stChunk + j * 512]);
        asm volatile("s_waitcnt vmcnt(4)" ::: "memory");   // stage(s+1) landed
        __builtin_amdgcn_s_barrier();
        __builtin_amdgcn_sched_barrier(0);
        {
            const int base = cB * 8192;
#pragma unroll
            for (int f = 0; f < 4; ++f) {
                avB[f] = *(const s8v*)&sL[base + aOff + f * 512 + lane * 8];
                bvB[f] = *(const s8v*)&sL[base + bOff + f * 512 + lane * 8];
            }
        }
#pragma unroll
        for (int ma = 0; ma < 4; ++ma)
#pragma unroll
            for (int nb = 0; nb < 4; ++nb)
                acc[ma][nb] = __builtin_amdgcn_mfma_f32_16x16x32_bf16(
                    avA[ma], bvA[nb], acc[ma][nb], 0, 0, 0);

        // ---- odd: execute step s+1, read step s+2, stage step s+3 ----
#pragma unroll
        for (int j = 0; j < 4; ++j)
            GLDS16(stSrc + (size_t)(s + 3) * 2048 + j * 512 + lane * 8,
                   &sL[cA * 8192 + stChunk + j * 512]);
        asm volatile("s_waitcnt vmcnt(4)" ::: "memory");   // stage(s+2) landed
        __builtin_amdgcn_s_barrier();
        __builtin_amdgcn_sched_barrier(0);
        {
            const int base = cC * 8192;
#pragma unroll
            for (int f = 0; f < 4; ++f) {
                avA[f] = *(const s8v*)&sL[base + aOff + f * 512 + lane * 8];
                bvA[f] = *(const s8v*)&sL[base + bOff + f * 512 + lane * 8];
            }
        }
#pragma unroll
        for (int ma = 0; ma < 4; ++ma)
#pragma unroll
            for (int nb = 0; nb < 4; ++nb)
                acc[ma][nb] = __builtin_amdgcn_mfma_f32_16x16x32_bf16(
                    avB[ma], bvB[nb], acc[ma][nb], 0, 0, 0);

        // rotate slots by two steps: (cA,cB,cC) <- (cC,cA,cB)
        int nA = cC, nB = cA, nC = cB;
        cA = nA; cB = nB; cC = nC;
    }

    // ---- tail: steps 52 (regs A, already loaded) and 53 ----
    asm volatile("s_waitcnt vmcnt(0)" ::: "memory");       // stage(53) landed
    __builtin_amdgcn_s_barrier();
    __builtin_amdgcn_sched_barrier(0);
    {
        const int base = cB * 8192;                        // slot of step 53
#pragma unroll
        for (int f = 0; f < 4; ++f) {
            avB[f] = *(const s8v*)&sL[base + aOff + f * 512 + lane * 8];
            bvB[f] = *(const s8v*)&sL[base + bOff + f * 512 + lane * 8];
        }
    }
#pragma unroll
    for (int ma = 0; ma < 4; ++ma)
#pragma unroll
        for (int nb = 0; nb < 4; ++nb)
            acc[ma][nb] = __builtin_amdgcn_mfma_f32_16x16x32_bf16(
                avA[ma], bvA[nb], acc[ma][nb], 0, 0, 0);
#pragma unroll
    for (int ma = 0; ma < 4; ++ma)
#pragma unroll
        for (int nb = 0; nb < 4; ++nb)
            acc[ma][nb] = __builtin_amdgcn_mfma_f32_16x16x32_bf16(
                avB[ma], bvB[nb], acc[ma][nb], 0, 0, 0);

    short* p = P + (size_t)blockIdx.z * 768 * HWPX;
#pragma unroll
    for (int ma = 0; ma < 4; ++ma)
#pragma unroll
        for (int nb = 0; nb < 4; ++nb)
#pragma unroll
            for (int r = 0; r < 4; ++r)
                p[(size_t)(mg * 64 + ma * 16 + quad * 4 + r) * HWPX
                  + pg * 64 + nb * 16 + lm] = (short)f2bf(acc[ma][nb][r]);
}

// out f32 = sum of 4 bf16 partials
__global__ __launch_bounds__(256)
void ep_dg_k(const short* __restrict__ P, float* __restrict__ out)
{
    int i = blockIdx.x * 256 + threadIdx.x;
    if (i >= 768 * HWPX / 8) return;
    size_t base = (size_t)i * 8;
    float s[8];
#pragma unroll
    for (int j = 0; j < 8; ++j) s[j] = 0.f;
    for (int sp = 0; sp < 4; ++sp) {
        uint4 v = *(const uint4*)&P[(size_t)sp * 768 * HWPX + base];
        s[0] += bf2f(v.x & 0xffffu); s[1] += bf2f(v.x >> 16);
        s[2] += bf2f(v.y & 0xffffu); s[3] += bf2f(v.y >> 16);
        s[4] += bf2f(v.z & 0xffffu); s[5] += bf2f(v.z >> 16);
        s[6] += bf2f(v.w & 0xffffu); s[7] += bf2f(v.w >> 16);
    }
    float4 o0 = make_float4(s[0], s[1], s[2], s[3]);
    float4 o1 = make_float4(s[4], s[5], s[6], s[7]);
    *(float4*)&out[base]     = o0;
    *(float4*)&out[base + 4] = o1;
}

// ---------------------------------------------------------------------------
extern "C" void kernel_launch(void* const* d_in, const int* in_sizes, int n_in,
                              void* d_out, int out_size, void* d_ws, size_t ws_size,
                              hipStream_t stream)
{
    const float* x_in  = (const float*)d_in[0];
    const float* x_ref = (const float*)d_in[1];
    const float* w1    = (const float*)d_in[2];
    const float* w2    = (const float*)d_in[3];
    const float* w3    = (const float*)d_in[4];
    const float* ow    = (const float*)d_in[5];
    const float* dw    = (const float*)d_in[6];
    float* out = (float*)d_out;

    char* w = (char*)d_ws;
    size_t off = 0;
    auto carve = [&](size_t bytes) {
        void* p = w + off;
        off += (bytes + 255) & ~(size_t)255;
        return p;
    };
    short* xcat = (short*)carve((size_t)4096 * 1536 * 2);        // 12.58 MB
    short* w1p  = (short*)carve((size_t)C1 * 2);                 //  5.31 MB (NB=4)
    short* w2p  = (short*)carve((size_t)(C2 - C1) * 2);          //  0.66 MB (NB=2)
    short* w3p  = (short*)carve((size_t)(C3 - C2) * 2);          //  5.31 MB (NB=4)
    short* w4p  = (short*)carve((size_t)(C4 - C3) * 2);          //  0.88 MB (NB=2)
    short* dwp  = (short*)carve((size_t)(C5 - C4) * 2);          // 10.62 MB (NB=4)
    float* offs = (float*)carve((size_t)18 * 4096 * 4);          //  0.29 MB
    short* Smp  = (short*)carve((size_t)4096 * 6912 * 2);        // 56.62 MB
    // REGION R: 25.17 MB, aliased across phases
    char*  R    = (char*)carve((size_t)2 * 768 * 4096 * 4);
    short* rh1  = (short*)R;                    // [4096][192] bf16
    short* rh2  = (short*)(R + 1572864);        // [4096][192] bf16
    short* est  = (short*)(R + 3145728);        // [4096][1536] bf16
    short* Pcv  = Smp;                          // conv partials (Smp idle til sample)
    short* Pdg  = (short*)R;                    // dgemm partials [4][768][4096] bf16

    tr_cat_k<<<dim3(24, 64), 256, 0, stream>>>(x_in, x_ref, xcat);
    wpack_all_k<<<(C5 + 255) / 256, 256, 0, stream>>>(w1, w2, w3, ow, dw,
                                                      w1p, w2p, w3p, w4p, dwp);

    const int n8 = 4096 * 192 / 8;
    // conv1: 1536->192 relu; N=64, ksplit 16 x 3 chunks; partials in Smp
    convf_k<4><<<dim3(16, 3, 16), 256, 0, stream>>>(xcat, 1536, w1p, 432, 3,
                                                    Pcv, 192, 4096 * 192);
    ep_sumb_k<<<(n8 + 255) / 256, 256, 0, stream>>>(Pcv, rh1, 16, (size_t)4096 * 192, n8, 1);
    // conv2: 192->192 relu; NB=2 (N=32) -> grid (16,6,6)=576 blocks, 2.25/CU
    convf_k<2><<<dim3(16, 6, 6), 256, 0, stream>>>(rh1, 192, w2p, 54, 1,
                                                   Pcv, 192, 4096 * 192);
    ep_sumb_k<<<(n8 + 255) / 256, 256, 0, stream>>>(Pcv, rh2, 6, (size_t)4096 * 192, n8, 1);
    // conv3: 192->1536; N=64, ksplit 2 x 3 chunks; partials in Smp -> est
    convf_k<4><<<dim3(16, 24, 2), 256, 0, stream>>>(rh2, 192, w3p, 54, 3,
                                                    Pcv, 1536, 4096 * 1536);
    {
        const int n8c3 = 4096 * 1536 / 8;
        ep_sumb_k<<<(n8c3 + 255) / 256, 256, 0, stream>>>(Pcv, est, 2, (size_t)4096 * 1536, n8c3, 0);
    }
    // conv4: 1536->18(pad 32); N=32, ksplit 48 x 1 chunk; partials in Smp
    convf_k<2><<<dim3(16, 1, 48), 256, 0, stream>>>(est, 1536, w4p, 432, 1,
                                                    Pcv, 32, 4096 * 32);
    ep_offs_k<<<(18 * HWPX + 255) / 256, 256, 0, stream>>>(Pcv, offs, 48);
    // deformable conv: coalesced-write sampling, pipelined LDS-staged GEMM
    sample_k<<<dim3(256, 4), 256, 0, stream>>>(xcat, offs, Smp);
    dgemm_k<<<dim3(32, 6, 4), 256, 0, stream>>>(dwp, Smp, Pdg);
    ep_dg_k<<<(768 * HWPX / 8 + 255) / 256, 256, 0, stream>>>(Pdg, out);
}

// Round 11
// 319.892 us; speedup vs baseline: 1.0403x; 1.0309x over previous
//
#include <hip/hip_runtime.h>

#define HWPX 4096   // 64*64 pixels

typedef short s8v  __attribute__((ext_vector_type(8)));   // 8 x bf16 (4 VGPR)
typedef float f4v  __attribute__((ext_vector_type(4)));   // 4 x f32  (MFMA C/D)

__device__ inline unsigned short f2bf(float f) {          // RNE f32 -> bf16
    unsigned u = __float_as_uint(f);
    return (unsigned short)((u + 0x7fffu + ((u >> 16) & 1u)) >> 16);
}
__device__ inline float bf2f(unsigned s) {
    return __uint_as_float(s << 16);
}

// async global->LDS, 16B per lane, wave-uniform LDS base + lane*16
#define GLDS16(gsrc, ldst) \
    __builtin_amdgcn_global_load_lds( \
        (const __attribute__((address_space(1))) unsigned int*)(gsrc), \
        (__attribute__((address_space(3))) unsigned int*)(ldst), 16, 0, 0)

#define C1 2654208   // w1: 3g*432s*4f*512
#define C2 2985984   // + w2: 6g*54s*2f*512 (NB=2)
#define C3 5640192   // + w3: 24*54*4*512
#define C4 6082560   // + w4: 1*432*2*512
#define C5 11390976  // + dw: 12*216*4*512

// ---------------------------------------------------------------------------
// Fused weight fragment-pack for all 5 weights.
// dst[g][s][f][lane][8] bf16; s = cb*9+t; lane: lm=cout, quad=k-part.
// ---------------------------------------------------------------------------
__device__ inline void wpack1(const float* __restrict__ src, short* __restrict__ dst,
                              int i, int Cin, int Cout, int S, int NB)
{
    int e = i & 7, lane = (i >> 3) & 63;
    int lm = lane & 15, quad = lane >> 4;
    int rest = i >> 9;
    int f = rest % NB;
    int s = (rest / NB) % S;
    int g = rest / (NB * S);
    int cout = g * (NB * 16) + f * 16 + lm;
    int cb = s / 9, t = s % 9;
    int ch = cb * 32 + quad * 8 + e;
    dst[i] = (cout < Cout) ? (short)f2bf(src[((size_t)cout * Cin + ch) * 9 + t]) : 0;
}

// ---------------------------------------------------------------------------
// Merged prep: blocks [0,1536) transpose+concat+cast x_in/x_ref -> xcat;
// blocks [1536, ...) fragment-pack the 5 weight tensors. Saves a dispatch.
// ---------------------------------------------------------------------------
__global__ __launch_bounds__(256)
void prep_k(const float* __restrict__ xa, const float* __restrict__ xb,
            short* __restrict__ xt,
            const float* __restrict__ s1, const float* __restrict__ s2,
            const float* __restrict__ s3, const float* __restrict__ s4,
            const float* __restrict__ s5,
            short* __restrict__ d1, short* __restrict__ d2,
            short* __restrict__ d3, short* __restrict__ d4,
            short* __restrict__ d5)
{
    __shared__ __align__(16) short T[64 * 72];
    const int tid = threadIdx.x;
    if (blockIdx.x < 1536) {
        const int b = blockIdx.x;
        const int c0 = (b % 24) * 64, p0 = (b / 24) * 64;
        for (int i = tid; i < 4096; i += 256) {
            int cl = i >> 6, pl = i & 63;
            int c = c0 + cl;
            float v = (c < 768) ? xa[(size_t)c * HWPX + p0 + pl]
                                : xb[(size_t)(c - 768) * HWPX + p0 + pl];
            T[pl * 72 + cl] = (short)f2bf(v);
        }
        __syncthreads();
        for (int i = tid; i < 512; i += 256) {
            int pl = i >> 3, part = i & 7;
            uint4 v = *(const uint4*)&T[pl * 72 + part * 8];
            *(uint4*)&xt[(size_t)(p0 + pl) * 1536 + c0 + part * 8] = v;
        }
    } else {
        int i = (blockIdx.x - 1536) * 256 + tid;
        if (i < C1)      wpack1(s1, d1, i,      1536, 192,  432, 4);
        else if (i < C2) wpack1(s2, d2, i - C1, 192,  192,  54,  2);
        else if (i < C3) wpack1(s3, d3, i - C2, 192,  1536, 54,  4);
        else if (i < C4) wpack1(s4, d4, i - C3, 1536, 18,   432, 2);
        else if (i < C5) wpack1(s5, d5, i - C4, 768,  768,  216, 4);
    }
}

// ---------------------------------------------------------------------------
// Flipped implicit-GEMM 3x3 conv, MFMA bf16. Block 256 thr = 4 waves.
// M = pixels (4 rows x 64), N = NB*16 couts (fragment-packed weights from
// global, prefetched one tap ahead). LDS: halo 6x66x40 = 31.7 KB.
// SUM2: halo staging reads TWO k-split partial tensors (Xt, Xt2) and sums
// them (f32 add, bf16 round) -- fuses the former conv3 epilogue into conv4.
// ---------------------------------------------------------------------------
template<int NB, bool SUM2>
__global__ __launch_bounds__(256, 3)
void convf_k(const short* __restrict__ Xt, const short* __restrict__ Xt2,
             int CinStr,
             const short* __restrict__ Wp, int S, int chunks,
             short* __restrict__ Out, int Cstr, int splitStride)
{
    __shared__ __align__(16) short sH[6 * 66 * 40];   // 31.7 KB
    const int tid = threadIdx.x, lane = tid & 63, wv = tid >> 6;
    const int lm = lane & 15, quad = lane >> 4;
    const int r0 = blockIdx.x * 4;            // 4 pixel rows
    const int g  = blockIdx.y;                // cout group of NB*16
    const int cb0 = blockIdx.z * chunks;
    short* out = Out + (size_t)blockIdx.z * splitStride;

    f4v acc[4][NB];
#pragma unroll
    for (int ma = 0; ma < 4; ++ma)
#pragma unroll
        for (int nb = 0; nb < NB; ++nb)
#pragma unroll
            for (int r = 0; r < 4; ++r) acc[ma][nb][r] = 0.f;

    for (int cc = 0; cc < chunks; ++cc) {
        const int cb = cb0 + cc;
        const short* wpB = Wp + ((size_t)(g * S + cb * 9) * NB) * 512 + lane * 8;
        // prefetch tap-0 weight frags (overlaps halo staging + barrier)
        s8v bb[NB];
#pragma unroll
        for (int f = 0; f < NB; ++f)
            bb[f] = *(const s8v*)&wpB[(size_t)f * 512];

        // ---- stage halo: 6 rows x 66 px x 32 ch (zero-padded) ----
        for (int i = tid; i < 1584; i += 256) {
            int slot = i >> 2, part = i & 3;
            int hr = slot / 66, px = slot % 66;
            int gy = r0 - 1 + hr, gx = px - 1;
            uint4 v = {0, 0, 0, 0};
            if (gy >= 0 && gy < 64 && gx >= 0 && gx < 64) {
                size_t base = (size_t)(gy * 64 + gx) * CinStr + cb * 32 + part * 8;
                v = *(const uint4*)&Xt[base];
                if (SUM2) {
                    uint4 v2 = *(const uint4*)&Xt2[base];
                    unsigned* a = (unsigned*)&v;
                    const unsigned* b = (const unsigned*)&v2;
#pragma unroll
                    for (int k = 0; k < 4; ++k) {
                        float lo = bf2f(a[k] & 0xffffu) + bf2f(b[k] & 0xffffu);
                        float hi = bf2f(a[k] >> 16)     + bf2f(b[k] >> 16);
                        a[k] = f2bf(lo) | ((unsigned)f2bf(hi) << 16);
                    }
                }
            }
            *(uint4*)&sH[slot * 40 + part * 8] = v;
        }
        __syncthreads();

#pragma unroll
        for (int t = 0; t < 9; ++t) {
            const int ty = t / 3, tx = t % 3;
            // prefetch next tap (t=8 overreads into the next carved region)
            s8v nxt[NB];
#pragma unroll
            for (int f = 0; f < NB; ++f)
                nxt[f] = *(const s8v*)&wpB[(size_t)((t + 1) * NB + f) * 512];
            s8v a[4];
#pragma unroll
            for (int ma = 0; ma < 4; ++ma)
                a[ma] = *(const s8v*)&sH[((wv + ty) * 66 + ma * 16 + lm + tx) * 40 + quad * 8];
#pragma unroll
            for (int ma = 0; ma < 4; ++ma)
#pragma unroll
                for (int nb = 0; nb < NB; ++nb)
                    acc[ma][nb] = __builtin_amdgcn_mfma_f32_16x16x32_bf16(
                        a[ma], bb[nb], acc[ma][nb], 0, 0, 0);
#pragma unroll
            for (int f = 0; f < NB; ++f) bb[f] = nxt[f];
        }
        __syncthreads();
    }

    const int py = (r0 + wv) * 64;
#pragma unroll
    for (int ma = 0; ma < 4; ++ma)
#pragma unroll
        for (int nb = 0; nb < NB; ++nb)
#pragma unroll
            for (int r = 0; r < 4; ++r)
                out[(size_t)(py + ma * 16 + quad * 4 + r) * Cstr
                    + g * (NB * 16) + nb * 16 + lm] = (short)f2bf(acc[ma][nb][r]);
}

// ---------------------------------------------------------------------------
// Sum bf16 K-split partials, optional relu, -> bf16
// ---------------------------------------------------------------------------
__global__ __launch_bounds__(256)
void ep_sumb_k(const short* __restrict__ P, short* __restrict__ outb,
               int nsplit, size_t splitStride, int n8, int relu)
{
    int i = blockIdx.x * 256 + threadIdx.x;
    if (i >= n8) return;
    size_t base = (size_t)i * 8;
    float s[8];
#pragma unroll
    for (int j = 0; j < 8; ++j) s[j] = 0.f;
    for (int sp = 0; sp < nsplit; ++sp) {
        uint4 v = *(const uint4*)&P[sp * splitStride + base];
        s[0] += bf2f(v.x & 0xffffu); s[1] += bf2f(v.x >> 16);
        s[2] += bf2f(v.y & 0xffffu); s[3] += bf2f(v.y >> 16);
        s[4] += bf2f(v.z & 0xffffu); s[5] += bf2f(v.z >> 16);
        s[6] += bf2f(v.w & 0xffffu); s[7] += bf2f(v.w >> 16);
    }
    if (relu) {
#pragma unroll
        for (int j = 0; j < 8; ++j) s[j] = fmaxf(s[j], 0.f);
    }
    uint4 o;
    o.x = f2bf(s[0]) | ((unsigned)f2bf(s[1]) << 16);
    o.y = f2bf(s[2]) | ((unsigned)f2bf(s[3]) << 16);
    o.z = f2bf(s[4]) | ((unsigned)f2bf(s[5]) << 16);
    o.w = f2bf(s[6]) | ((unsigned)f2bf(s[7]) << 16);
    *(uint4*)&outb[base] = o;
}

// conv4 epilogue: partials bf16 [nsplit][4096][32] -> offs f32 [18][4096]
__global__ __launch_bounds__(256)
void ep_offs_k(const short* __restrict__ P, float* __restrict__ offs, int nsplit)
{
    int i = blockIdx.x * 256 + threadIdx.x;
    if (i >= 18 * HWPX) return;
    int m = i >> 12, px = i & 4095;
    float s = 0.f;
    for (int sp = 0; sp < nsplit; ++sp)
        s += bf2f((unsigned short)P[((size_t)sp * HWPX + px) * 32 + m]);
    offs[i] = s;
}

// ---------------------------------------------------------------------------
// Bilinear sampling v2 -> Smp fragment-packed, WAVE-COALESCED writes.
// ---------------------------------------------------------------------------
__global__ __launch_bounds__(256)
void sample_k(const short* __restrict__ xcat, const float* __restrict__ offs,
              short* __restrict__ Smp)
{
    __shared__ int   s_mi[9][16][4];
    __shared__ float s_mw[9][16][4];
    const int tid = threadIdx.x;
    const int p0  = blockIdx.x * 16;
    const int cbq = blockIdx.y * 6;    // 6 of 24 channel-blocks (32ch each)
    const int wv  = tid >> 6, lane = tid & 63;
    const int lmx = lane & 15, qd = lane >> 4;
    const int pg  = p0 >> 6, ma = (p0 >> 4) & 3;

    if (tid < 144) {
        int t = tid / 16, p = tid % 16;
        int pxg = p0 + p;
        int r = pxg >> 6, x = pxg & 63;
        float dy = offs[(size_t)(2 * t)     * HWPX + pxg];
        float dx = offs[(size_t)(2 * t + 1) * HWPX + pxg];
        float py  = (float)(r - 1 + t / 3) + dy;
        float pxf = (float)(x - 1 + t % 3) + dx;
        py  = fminf(fmaxf(py,  -1e6f), 1e6f);
        pxf = fminf(fmaxf(pxf, -1e6f), 1e6f);
        float y0f = floorf(py), x0f = floorf(pxf);
        float wy1 = py - y0f, wx1 = pxf - x0f;
        float wy0 = 1.f - wy1, wx0 = 1.f - wx1;
        bool vy0 = (y0f >=  0.f) && (y0f <= 63.f);
        bool vy1 = (y0f >= -1.f) && (y0f <= 62.f);
        bool vx0 = (x0f >=  0.f) && (x0f <= 63.f);
        bool vx1 = (x0f >= -1.f) && (x0f <= 62.f);
        int y0 = (int)fminf(fmaxf(y0f,       0.f), 63.f);
        int y1 = (int)fminf(fmaxf(y0f + 1.f, 0.f), 63.f);
        int x0 = (int)fminf(fmaxf(x0f,       0.f), 63.f);
        int x1 = (int)fminf(fmaxf(x0f + 1.f, 0.f), 63.f);
        s_mi[t][p][0] = y0 * 64 + x0;  s_mw[t][p][0] = (vy0 && vx0) ? wy0 * wx0 : 0.f;
        s_mi[t][p][1] = y0 * 64 + x1;  s_mw[t][p][1] = (vy0 && vx1) ? wy0 * wx1 : 0.f;
        s_mi[t][p][2] = y1 * 64 + x0;  s_mw[t][p][2] = (vy1 && vx0) ? wy1 * wx0 : 0.f;
        s_mi[t][p][3] = y1 * 64 + x1;  s_mw[t][p][3] = (vy1 && vx1) ? wy1 * wx1 : 0.f;
    }
    __syncthreads();

    for (int j = wv; j < 54; j += 4) {
        const int t = j / 6, cb = cbq + j % 6;
        int   mi[4];
        float mw[4];
#pragma unroll
        for (int c = 0; c < 4; ++c) {
            mi[c] = s_mi[t][lmx][c];
            mw[c] = s_mw[t][lmx][c];
        }
        float a[8];
#pragma unroll
        for (int k = 0; k < 8; ++k) a[k] = 0.f;
#pragma unroll
        for (int c = 0; c < 4; ++c) {
            float wgt = mw[c];
            const short* src = xcat + (size_t)mi[c] * 1536 + 768 + cb * 32 + qd * 8;
            uint4 v = *(const uint4*)src;
            a[0] += wgt * bf2f(v.x & 0xffffu); a[1] += wgt * bf2f(v.x >> 16);
            a[2] += wgt * bf2f(v.y & 0xffffu); a[3] += wgt * bf2f(v.y >> 16);
            a[4] += wgt * bf2f(v.z & 0xffffu); a[5] += wgt * bf2f(v.z >> 16);
            a[6] += wgt * bf2f(v.w & 0xffffu); a[7] += wgt * bf2f(v.w >> 16);
        }
        uint4 o;
        o.x = f2bf(a[0]) | ((unsigned)f2bf(a[1]) << 16);
        o.y = f2bf(a[2]) | ((unsigned)f2bf(a[3]) << 16);
        o.z = f2bf(a[4]) | ((unsigned)f2bf(a[5]) << 16);
        o.w = f2bf(a[6]) | ((unsigned)f2bf(a[7]) << 16);
        size_t addr = ((((size_t)pg * 216 + cb * 9 + t) * 4 + ma) * 64 + lane) * 8;
        *(uint4*)&Smp[addr] = o;
    }
}

// ---------------------------------------------------------------------------
// Deform GEMM v4 (best verified, R8): LDS staging (3-slot, global_load_lds,
// counted vmcnt) + one-step-ahead LDS->reg prefetch: MFMA(step s) runs on
// registers loaded LAST step while this step's ds_reads fill the DS pipe.
// Unroll x2 with named reg sets A/B; slot rotation (cA,cB,cC)<-(cC,cA,cB).
// ---------------------------------------------------------------------------
__global__ __launch_bounds__(256, 3)
void dgemm_k(const short* __restrict__ Ap, const short* __restrict__ Bp,
             short* __restrict__ P)
{
    __shared__ __align__(16) short sL[3 * 8192];   // 3 slots x 16 KB

    const int tid = threadIdx.x, lane = tid & 63, wv = tid >> 6;
    const int lm = lane & 15, quad = lane >> 4;
    const int mg = blockIdx.y * 2 + (wv >> 1);    // 64-cout group 0..11
    const int pg = blockIdx.x * 2 + (wv & 1);     // 64-px group 0..63
    const int s0 = blockIdx.z * 54;

    // staging role: wave wv copies one 4KB chunk per s-step
    const short* stSrc;
    int stChunk;
    if (wv < 2) {
        stSrc = Ap + ((size_t)(blockIdx.y * 2 + wv) * 216 + s0) * 2048;
        stChunk = wv * 2048;
    } else {
        stSrc = Bp + ((size_t)(blockIdx.x * 2 + (wv - 2)) * 216 + s0) * 2048;
        stChunk = 4096 + (wv - 2) * 2048;
    }

    f4v acc[4][4];
#pragma unroll
    for (int ma = 0; ma < 4; ++ma)
#pragma unroll
        for (int nb = 0; nb < 4; ++nb)
#pragma unroll
            for (int r = 0; r < 4; ++r) acc[ma][nb][r] = 0.f;

    // prologue: stage s=0 -> slot0, s=1 -> slot1
#pragma unroll
    for (int j = 0; j < 4; ++j)
        GLDS16(stSrc + (size_t)0 * 2048 + j * 512 + lane * 8,
               &sL[0 * 8192 + stChunk + j * 512]);
#pragma unroll
    for (int j = 0; j < 4; ++j)
        GLDS16(stSrc + (size_t)1 * 2048 + j * 512 + lane * 8,
               &sL[1 * 8192 + stChunk + j * 512]);
    asm volatile("s_waitcnt vmcnt(4)" ::: "memory");   // stage(0) landed (own)
    __builtin_amdgcn_s_barrier();                      // ... by all waves
    __builtin_amdgcn_sched_barrier(0);

    const int aOff = (wv >> 1) * 2048;
    const int bOff = 4096 + (wv & 1) * 2048;

    s8v avA[4], bvA[4], avB[4], bvB[4];
    // read slot0 -> regs A (frags for step 0)
#pragma unroll
    for (int f = 0; f < 4; ++f) {
        avA[f] = *(const s8v*)&sL[0 * 8192 + aOff + f * 512 + lane * 8];
        bvA[f] = *(const s8v*)&sL[0 * 8192 + bOff + f * 512 + lane * 8];
    }

    int cA = 0, cB = 1, cC = 2;   // slots of steps s, s+1, s+2

    for (int s = 0; s < 52; s += 2) {
        // ---- even: execute step s, read step s+1, stage step s+2 ----
#pragma unroll
        for (int j = 0; j < 4; ++j)
            GLDS16(stSrc + (size_t)(s + 2) * 2048 + j * 512 + lane * 8,
                   &sL[cC * 8192 + stChunk + j * 512]);
        asm volatile("s_waitcnt vmcnt(4)" ::: "memory");   // stage(s+1) landed
        __builtin_amdgcn_s_barrier();
        __builtin_amdgcn_sched_barrier(0);
        {
            const int base = cB * 8192;
#pragma unroll
            for (int f = 0; f < 4; ++f) {
                avB[f] = *(const s8v*)&sL[base + aOff + f * 512 + lane * 8];
                bvB[f] = *(const s8v*)&sL[base + bOff + f * 512 + lane * 8];
            }
        }
#pragma unroll
        for (int ma = 0; ma < 4; ++ma)
#pragma unroll
            for (int nb = 0; nb < 4; ++nb)
                acc[ma][nb] = __builtin_amdgcn_mfma_f32_16x16x32_bf16(
                    avA[ma], bvA[nb], acc[ma][nb], 0, 0, 0);

        // ---- odd: execute step s+1, read step s+2, stage step s+3 ----
#pragma unroll
        for (int j = 0; j < 4; ++j)
            GLDS16(stSrc + (size_t)(s + 3) * 2048 + j * 512 + lane * 8,
                   &sL[cA * 8192 + stChunk + j * 512]);
        asm volatile("s_waitcnt vmcnt(4)" ::: "memory");   // stage(s+2) landed
        __builtin_amdgcn_s_barrier();
        __builtin_amdgcn_sched_barrier(0);
        {
            const int base = cC * 8192;
#pragma unroll
            for (int f = 0; f < 4; ++f) {
                avA[f] = *(const s8v*)&sL[base + aOff + f * 512 + lane * 8];
                bvA[f] = *(const s8v*)&sL[base + bOff + f * 512 + lane * 8];
            }
        }
#pragma unroll
        for (int ma = 0; ma < 4; ++ma)
#pragma unroll
            for (int nb = 0; nb < 4; ++nb)
                acc[ma][nb] = __builtin_amdgcn_mfma_f32_16x16x32_bf16(
                    avB[ma], bvB[nb], acc[ma][nb], 0, 0, 0);

        // rotate slots by two steps: (cA,cB,cC) <- (cC,cA,cB)
        int nA = cC, nB = cA, nC = cB;
        cA = nA; cB = nB; cC = nC;
    }

    // ---- tail: steps 52 (regs A, already loaded) and 53 ----
    asm volatile("s_waitcnt vmcnt(0)" ::: "memory");       // stage(53) landed
    __builtin_amdgcn_s_barrier();
    __builtin_amdgcn_sched_barrier(0);
    {
        const int base = cB * 8192;                        // slot of step 53
#pragma unroll
        for (int f = 0; f < 4; ++f) {
            avB[f] = *(const s8v*)&sL[base + aOff + f * 512 + lane * 8];
            bvB[f] = *(const s8v*)&sL[base + bOff + f * 512 + lane * 8];
        }
    }
#pragma unroll
    for (int ma = 0; ma < 4; ++ma)
#pragma unroll
        for (int nb = 0; nb < 4; ++nb)
            acc[ma][nb] = __builtin_amdgcn_mfma_f32_16x16x32_bf16(
                avA[ma], bvA[nb], acc[ma][nb], 0, 0, 0);
#pragma unroll
    for (int ma = 0; ma < 4; ++ma)
#pragma unroll
        for (int nb = 0; nb < 4; ++nb)
            acc[ma][nb] = __builtin_amdgcn_mfma_f32_16x16x32_bf16(
                avB[ma], bvB[nb], acc[ma][nb], 0, 0, 0);

    short* p = P + (size_t)blockIdx.z * 768 * HWPX;
#pragma unroll
    for (int ma = 0; ma < 4; ++ma)
#pragma unroll
        for (int nb = 0; nb < 4; ++nb)
#pragma unroll
            for (int r = 0; r < 4; ++r)
                p[(size_t)(mg * 64 + ma * 16 + quad * 4 + r) * HWPX
                  + pg * 64 + nb * 16 + lm] = (short)f2bf(acc[ma][nb][r]);
}

// out f32 = sum of 4 bf16 partials
__global__ __launch_bounds__(256)
void ep_dg_k(const short* __restrict__ P, float* __restrict__ out)
{
    int i = blockIdx.x * 256 + threadIdx.x;
    if (i >= 768 * HWPX / 8) return;
    size_t base = (size_t)i * 8;
    float s[8];
#pragma unroll
    for (int j = 0; j < 8; ++j) s[j] = 0.f;
    for (int sp = 0; sp < 4; ++sp) {
        uint4 v = *(const uint4*)&P[(size_t)sp * 768 * HWPX + base];
        s[0] += bf2f(v.x & 0xffffu); s[1] += bf2f(v.x >> 16);
        s[2] += bf2f(v.y & 0xffffu); s[3] += bf2f(v.y >> 16);
        s[4] += bf2f(v.z & 0xffffu); s[5] += bf2f(v.z >> 16);
        s[6] += bf2f(v.w & 0xffffu); s[7] += bf2f(v.w >> 16);
    }
    float4 o0 = make_float4(s[0], s[1], s[2], s[3]);
    float4 o1 = make_float4(s[4], s[5], s[6], s[7]);
    *(float4*)&out[base]     = o0;
    *(float4*)&out[base + 4] = o1;
}

// ---------------------------------------------------------------------------
extern "C" void kernel_launch(void* const* d_in, const int* in_sizes, int n_in,
                              void* d_out, int out_size, void* d_ws, size_t ws_size,
                              hipStream_t stream)
{
    const float* x_in  = (const float*)d_in[0];
    const float* x_ref = (const float*)d_in[1];
    const float* w1    = (const float*)d_in[2];
    const float* w2    = (const float*)d_in[3];
    const float* w3    = (const float*)d_in[4];
    const float* ow    = (const float*)d_in[5];
    const float* dw    = (const float*)d_in[6];
    float* out = (float*)d_out;

    char* w = (char*)d_ws;
    size_t off = 0;
    auto carve = [&](size_t bytes) {
        void* p = w + off;
        off += (bytes + 255) & ~(size_t)255;
        return p;
    };
    short* xcat = (short*)carve((size_t)4096 * 1536 * 2);        // 12.58 MB
    short* w1p  = (short*)carve((size_t)C1 * 2);                 //  5.31 MB (NB=4)
    short* w2p  = (short*)carve((size_t)(C2 - C1) * 2);          //  0.66 MB (NB=2)
    short* w3p  = (short*)carve((size_t)(C3 - C2) * 2);          //  5.31 MB (NB=4)
    short* w4p  = (short*)carve((size_t)(C4 - C3) * 2);          //  0.88 MB (NB=2)
    short* dwp  = (short*)carve((size_t)(C5 - C4) * 2);          // 10.62 MB (NB=4)
    float* offs = (float*)carve((size_t)18 * 4096 * 4);          //  0.29 MB
    short* Smp  = (short*)carve((size_t)4096 * 6912 * 2);        // 56.62 MB
    // REGION R: 25.17 MB, aliased across phases
    char*  R    = (char*)carve((size_t)2 * 768 * 4096 * 4);
    short* rh1  = (short*)R;                    // [4096][192] bf16
    short* rh2  = (short*)(R + 1572864);        // [4096][192] bf16
    short* p4   = (short*)(R + 3145728);        // conv4 partials [48][4096][32]
    short* Pcv  = Smp;                          // conv partials (Smp idle til sample)
    short* Pdg  = (short*)R;                    // dgemm partials [4][768][4096] bf16

    // prep: transpose/concat (1536 blocks) + weight pack ((C5+255)/256 blocks)
    prep_k<<<1536 + (C5 + 255) / 256, 256, 0, stream>>>(
        x_in, x_ref, xcat, w1, w2, w3, ow, dw, w1p, w2p, w3p, w4p, dwp);

    const int n8 = 4096 * 192 / 8;
    // conv1: 1536->192 relu; N=64, ksplit 16 x 3 chunks; partials in Smp
    convf_k<4, false><<<dim3(16, 3, 16), 256, 0, stream>>>(
        xcat, nullptr, 1536, w1p, 432, 3, Pcv, 192, 4096 * 192);
    ep_sumb_k<<<(n8 + 255) / 256, 256, 0, stream>>>(Pcv, rh1, 16, (size_t)4096 * 192, n8, 1);
    // conv2: 192->192 relu; NB=2 (N=32) -> grid (16,6,6)=576 blocks, 2.25/CU
    convf_k<2, false><<<dim3(16, 6, 6), 256, 0, stream>>>(
        rh1, nullptr, 192, w2p, 54, 1, Pcv, 192, 4096 * 192);
    ep_sumb_k<<<(n8 + 255) / 256, 256, 0, stream>>>(Pcv, rh2, 6, (size_t)4096 * 192, n8, 1);
    // conv3: 192->1536; N=64, ksplit 2 x 3 chunks; partials stay in Smp
    convf_k<4, false><<<dim3(16, 24, 2), 256, 0, stream>>>(
        rh2, nullptr, 192, w3p, 54, 3, Pcv, 1536, 4096 * 1536);
    // conv4: 1536->18(pad 32); input = SUM of conv3's 2 partials (fused
    // epilogue during halo staging); partials -> p4 (R region, est slot)
    convf_k<2, true><<<dim3(16, 1, 48), 256, 0, stream>>>(
        Pcv, Pcv + (size_t)4096 * 1536, 1536, w4p, 432, 1, p4, 32, 4096 * 32);
    ep_offs_k<<<(18 * HWPX + 255) / 256, 256, 0, stream>>>(p4, offs, 48);
    // deformable conv: coalesced-write sampling, pipelined LDS-staged GEMM
    sample_k<<<dim3(256, 4), 256, 0, stream>>>(xcat, offs, Smp);
    dgemm_k<<<dim3(32, 6, 4), 256, 0, stream>>>(dwp, Smp, Pdg);
    ep_dg_k<<<(768 * HWPX / 8 + 255) / 256, 256, 0, stream>>>(Pdg, out);
}

// Round 12
// 305.599 us; speedup vs baseline: 1.0890x; 1.0468x over previous
//
#include <hip/hip_runtime.h>

#define HWPX 4096   // 64*64 pixels

typedef short s8v  __attribute__((ext_vector_type(8)));   // 8 x bf16 (4 VGPR)
typedef float f4v  __attribute__((ext_vector_type(4)));   // 4 x f32  (MFMA C/D)

__device__ inline unsigned short f2bf(float f) {          // RNE f32 -> bf16
    unsigned u = __float_as_uint(f);
    return (unsigned short)((u + 0x7fffu + ((u >> 16) & 1u)) >> 16);
}
__device__ inline float bf2f(unsigned s) {
    return __uint_as_float(s << 16);
}

// async global->LDS, 16B per lane, wave-uniform LDS base + lane*16
#define GLDS16(gsrc, ldst) \
    __builtin_amdgcn_global_load_lds( \
        (const __attribute__((address_space(1))) unsigned int*)(gsrc), \
        (__attribute__((address_space(3))) unsigned int*)(ldst), 16, 0, 0)

#define C1 2654208   // w1: 3g*432s*4f*512
#define C2 2985984   // + w2: 6g*54s*2f*512 (NB=2)
#define C3 5640192   // + w3: 24*54*4*512
#define C4 6082560   // + w4: 1*432*2*512
#define C5 11390976  // + dw: 12*216*4*512

// ---------------------------------------------------------------------------
// Wave-level weight fragment-pack: one wave handles (g, cb, f).
// Per lane (lm=cout-in-group, quad=k-part): reads 72 CONTIGUOUS floats
// (8 e x 9 t = 288B, 18 aligned float4s), emits 9 coalesced 1KB wave-stores
// (one uint4 of 8 bf16 per t). Output byte-identical to the old wpack1.
// ---------------------------------------------------------------------------
__device__ __forceinline__ void wpack_wave(const float* __restrict__ src,
                                           short* __restrict__ dst,
                                           int g, int cb, int f, int lane,
                                           int Cin, int Cout, int S, int NB)
{
    const int lm = lane & 15, quad = lane >> 4;
    const int cout = g * (NB * 16) + f * 16 + lm;
    float r[72];
    if (cout < Cout) {
        const float* p = src + ((size_t)cout * Cin + cb * 32) * 9 + quad * 72;
#pragma unroll
        for (int j = 0; j < 18; ++j) {
            float4 v = *(const float4*)(p + j * 4);
            r[j * 4 + 0] = v.x; r[j * 4 + 1] = v.y;
            r[j * 4 + 2] = v.z; r[j * 4 + 3] = v.w;
        }
    } else {
#pragma unroll
        for (int j = 0; j < 72; ++j) r[j] = 0.f;
    }
#pragma unroll
    for (int t = 0; t < 9; ++t) {
        uint4 o;
        o.x = f2bf(r[0 * 9 + t]) | ((unsigned)f2bf(r[1 * 9 + t]) << 16);
        o.y = f2bf(r[2 * 9 + t]) | ((unsigned)f2bf(r[3 * 9 + t]) << 16);
        o.z = f2bf(r[4 * 9 + t]) | ((unsigned)f2bf(r[5 * 9 + t]) << 16);
        o.w = f2bf(r[6 * 9 + t]) | ((unsigned)f2bf(r[7 * 9 + t]) << 16);
        *(uint4*)&dst[((size_t)(g * S + cb * 9 + t) * NB + f) * 512 + lane * 8] = o;
    }
}

// ---------------------------------------------------------------------------
// Merged prep: blocks [0,1536) transpose+concat+cast x_in/x_ref -> xcat;
// blocks [1536, 1536+618) wave-pack the 5 weight tensors (2472 waves).
// ---------------------------------------------------------------------------
__global__ __launch_bounds__(256)
void prep_k(const float* __restrict__ xa, const float* __restrict__ xb,
            short* __restrict__ xt,
            const float* __restrict__ s1, const float* __restrict__ s2,
            const float* __restrict__ s3, const float* __restrict__ s4,
            const float* __restrict__ s5,
            short* __restrict__ d1, short* __restrict__ d2,
            short* __restrict__ d3, short* __restrict__ d4,
            short* __restrict__ d5)
{
    __shared__ __align__(16) short T[64 * 72];
    const int tid = threadIdx.x;
    if (blockIdx.x < 1536) {
        const int b = blockIdx.x;
        const int c0 = (b % 24) * 64, p0 = (b / 24) * 64;
        for (int i = tid; i < 4096; i += 256) {
            int cl = i >> 6, pl = i & 63;
            int c = c0 + cl;
            float v = (c < 768) ? xa[(size_t)c * HWPX + p0 + pl]
                                : xb[(size_t)(c - 768) * HWPX + p0 + pl];
            T[pl * 72 + cl] = (short)f2bf(v);
        }
        __syncthreads();
        for (int i = tid; i < 512; i += 256) {
            int pl = i >> 3, part = i & 7;
            uint4 v = *(const uint4*)&T[pl * 72 + part * 8];
            *(uint4*)&xt[(size_t)(p0 + pl) * 1536 + c0 + part * 8] = v;
        }
    } else {
        // wave id; segments: w1 576 | w2 72 | w3 576 | w4 96 | dw 1152 = 2472
        const int wid = (blockIdx.x - 1536) * 4 + (tid >> 6);
        const int lane = tid & 63;
        if (wid < 576) {
            int id = wid;                 // g*48*4 + cb*4 + f
            wpack_wave(s1, d1, id / 192, (id / 4) % 48, id & 3, lane, 1536, 192, 432, 4);
        } else if (wid < 648) {
            int id = wid - 576;           // g*6*2 + cb*2 + f
            wpack_wave(s2, d2, id / 12, (id / 2) % 6, id & 1, lane, 192, 192, 54, 2);
        } else if (wid < 1224) {
            int id = wid - 648;           // g*6*4 + cb*4 + f
            wpack_wave(s3, d3, id / 24, (id / 4) % 6, id & 3, lane, 192, 1536, 54, 4);
        } else if (wid < 1320) {
            int id = wid - 1224;          // g*48*2 + cb*2 + f
            wpack_wave(s4, d4, id / 96, (id / 2) % 48, id & 1, lane, 1536, 18, 432, 2);
        } else if (wid < 2472) {
            int id = wid - 1320;          // g*24*4 + cb*4 + f
            wpack_wave(s5, d5, id / 96, (id / 4) % 24, id & 3, lane, 768, 768, 216, 4);
        }
    }
}

// ---------------------------------------------------------------------------
// Flipped implicit-GEMM 3x3 conv, MFMA bf16. Block 256 thr = 4 waves.
// M = pixels (4 rows x 64), N = NB*16 couts (fragment-packed weights from
// global, prefetched one tap ahead). LDS: halo 6x66x40 = 31.7 KB.
// SUM2: halo staging reads TWO k-split partial tensors (Xt, Xt2) and sums
// them (f32 add, bf16 round) -- fuses the former conv3 epilogue into conv4.
// ---------------------------------------------------------------------------
template<int NB, bool SUM2>
__global__ __launch_bounds__(256, 3)
void convf_k(const short* __restrict__ Xt, const short* __restrict__ Xt2,
             int CinStr,
             const short* __restrict__ Wp, int S, int chunks,
             short* __restrict__ Out, int Cstr, int splitStride)
{
    __shared__ __align__(16) short sH[6 * 66 * 40];   // 31.7 KB
    const int tid = threadIdx.x, lane = tid & 63, wv = tid >> 6;
    const int lm = lane & 15, quad = lane >> 4;
    const int r0 = blockIdx.x * 4;            // 4 pixel rows
    const int g  = blockIdx.y;                // cout group of NB*16
    const int cb0 = blockIdx.z * chunks;
    short* out = Out + (size_t)blockIdx.z * splitStride;

    f4v acc[4][NB];
#pragma unroll
    for (int ma = 0; ma < 4; ++ma)
#pragma unroll
        for (int nb = 0; nb < NB; ++nb)
#pragma unroll
            for (int r = 0; r < 4; ++r) acc[ma][nb][r] = 0.f;

    for (int cc = 0; cc < chunks; ++cc) {
        const int cb = cb0 + cc;
        const short* wpB = Wp + ((size_t)(g * S + cb * 9) * NB) * 512 + lane * 8;
        // prefetch tap-0 weight frags (overlaps halo staging + barrier)
        s8v bb[NB];
#pragma unroll
        for (int f = 0; f < NB; ++f)
            bb[f] = *(const s8v*)&wpB[(size_t)f * 512];

        // ---- stage halo: 6 rows x 66 px x 32 ch (zero-padded) ----
        for (int i = tid; i < 1584; i += 256) {
            int slot = i >> 2, part = i & 3;
            int hr = slot / 66, px = slot % 66;
            int gy = r0 - 1 + hr, gx = px - 1;
            uint4 v = {0, 0, 0, 0};
            if (gy >= 0 && gy < 64 && gx >= 0 && gx < 64) {
                size_t base = (size_t)(gy * 64 + gx) * CinStr + cb * 32 + part * 8;
                v = *(const uint4*)&Xt[base];
                if (SUM2) {
                    uint4 v2 = *(const uint4*)&Xt2[base];
                    unsigned* a = (unsigned*)&v;
                    const unsigned* b = (const unsigned*)&v2;
#pragma unroll
                    for (int k = 0; k < 4; ++k) {
                        float lo = bf2f(a[k] & 0xffffu) + bf2f(b[k] & 0xffffu);
                        float hi = bf2f(a[k] >> 16)     + bf2f(b[k] >> 16);
                        a[k] = f2bf(lo) | ((unsigned)f2bf(hi) << 16);
                    }
                }
            }
            *(uint4*)&sH[slot * 40 + part * 8] = v;
        }
        __syncthreads();

#pragma unroll
        for (int t = 0; t < 9; ++t) {
            const int ty = t / 3, tx = t % 3;
            // prefetch next tap (t=8 overreads into the next carved region)
            s8v nxt[NB];
#pragma unroll
            for (int f = 0; f < NB; ++f)
                nxt[f] = *(const s8v*)&wpB[(size_t)((t + 1) * NB + f) * 512];
            s8v a[4];
#pragma unroll
            for (int ma = 0; ma < 4; ++ma)
                a[ma] = *(const s8v*)&sH[((wv + ty) * 66 + ma * 16 + lm + tx) * 40 + quad * 8];
#pragma unroll
            for (int ma = 0; ma < 4; ++ma)
#pragma unroll
                for (int nb = 0; nb < NB; ++nb)
                    acc[ma][nb] = __builtin_amdgcn_mfma_f32_16x16x32_bf16(
                        a[ma], bb[nb], acc[ma][nb], 0, 0, 0);
#pragma unroll
            for (int f = 0; f < NB; ++f) bb[f] = nxt[f];
        }
        __syncthreads();
    }

    const int py = (r0 + wv) * 64;
#pragma unroll
    for (int ma = 0; ma < 4; ++ma)
#pragma unroll
        for (int nb = 0; nb < NB; ++nb)
#pragma unroll
            for (int r = 0; r < 4; ++r)
                out[(size_t)(py + ma * 16 + quad * 4 + r) * Cstr
                    + g * (NB * 16) + nb * 16 + lm] = (short)f2bf(acc[ma][nb][r]);
}

// ---------------------------------------------------------------------------
// Sum bf16 K-split partials, optional relu, -> bf16
// ---------------------------------------------------------------------------
__global__ __launch_bounds__(256)
void ep_sumb_k(const short* __restrict__ P, short* __restrict__ outb,
               int nsplit, size_t splitStride, int n8, int relu)
{
    int i = blockIdx.x * 256 + threadIdx.x;
    if (i >= n8) return;
    size_t base = (size_t)i * 8;
    float s[8];
#pragma unroll
    for (int j = 0; j < 8; ++j) s[j] = 0.f;
    for (int sp = 0; sp < nsplit; ++sp) {
        uint4 v = *(const uint4*)&P[sp * splitStride + base];
        s[0] += bf2f(v.x & 0xffffu); s[1] += bf2f(v.x >> 16);
        s[2] += bf2f(v.y & 0xffffu); s[3] += bf2f(v.y >> 16);
        s[4] += bf2f(v.z & 0xffffu); s[5] += bf2f(v.z >> 16);
        s[6] += bf2f(v.w & 0xffffu); s[7] += bf2f(v.w >> 16);
    }
    if (relu) {
#pragma unroll
        for (int j = 0; j < 8; ++j) s[j] = fmaxf(s[j], 0.f);
    }
    uint4 o;
    o.x = f2bf(s[0]) | ((unsigned)f2bf(s[1]) << 16);
    o.y = f2bf(s[2]) | ((unsigned)f2bf(s[3]) << 16);
    o.z = f2bf(s[4]) | ((unsigned)f2bf(s[5]) << 16);
    o.w = f2bf(s[6]) | ((unsigned)f2bf(s[7]) << 16);
    *(uint4*)&outb[base] = o;
}

// conv4 epilogue: partials bf16 [nsplit][4096][32] -> offs f32 [18][4096]
__global__ __launch_bounds__(256)
void ep_offs_k(const short* __restrict__ P, float* __restrict__ offs, int nsplit)
{
    int i = blockIdx.x * 256 + threadIdx.x;
    if (i >= 18 * HWPX) return;
    int m = i >> 12, px = i & 4095;
    float s = 0.f;
    for (int sp = 0; sp < nsplit; ++sp)
        s += bf2f((unsigned short)P[((size_t)sp * HWPX + px) * 32 + m]);
    offs[i] = s;
}

// ---------------------------------------------------------------------------
// Bilinear sampling v2 -> Smp fragment-packed, WAVE-COALESCED writes.
// ---------------------------------------------------------------------------
__global__ __launch_bounds__(256)
void sample_k(const short* __restrict__ xcat, const float* __restrict__ offs,
              short* __restrict__ Smp)
{
    __shared__ int   s_mi[9][16][4];
    __shared__ float s_mw[9][16][4];
    const int tid = threadIdx.x;
    const int p0  = blockIdx.x * 16;
    const int cbq = blockIdx.y * 6;    // 6 of 24 channel-blocks (32ch each)
    const int wv  = tid >> 6, lane = tid & 63;
    const int lmx = lane & 15, qd = lane >> 4;
    const int pg  = p0 >> 6, ma = (p0 >> 4) & 3;

    if (tid < 144) {
        int t = tid / 16, p = tid % 16;
        int pxg = p0 + p;
        int r = pxg >> 6, x = pxg & 63;
        float dy = offs[(size_t)(2 * t)     * HWPX + pxg];
        float dx = offs[(size_t)(2 * t + 1) * HWPX + pxg];
        float py  = (float)(r - 1 + t / 3) + dy;
        float pxf = (float)(x - 1 + t % 3) + dx;
        py  = fminf(fmaxf(py,  -1e6f), 1e6f);
        pxf = fminf(fmaxf(pxf, -1e6f), 1e6f);
        float y0f = floorf(py), x0f = floorf(pxf);
        float wy1 = py - y0f, wx1 = pxf - x0f;
        float wy0 = 1.f - wy1, wx0 = 1.f - wx1;
        bool vy0 = (y0f >=  0.f) && (y0f <= 63.f);
        bool vy1 = (y0f >= -1.f) && (y0f <= 62.f);
        bool vx0 = (x0f >=  0.f) && (x0f <= 63.f);
        bool vx1 = (x0f >= -1.f) && (x0f <= 62.f);
        int y0 = (int)fminf(fmaxf(y0f,       0.f), 63.f);
        int y1 = (int)fminf(fmaxf(y0f + 1.f, 0.f), 63.f);
        int x0 = (int)fminf(fmaxf(x0f,       0.f), 63.f);
        int x1 = (int)fminf(fmaxf(x0f + 1.f, 0.f), 63.f);
        s_mi[t][p][0] = y0 * 64 + x0;  s_mw[t][p][0] = (vy0 && vx0) ? wy0 * wx0 : 0.f;
        s_mi[t][p][1] = y0 * 64 + x1;  s_mw[t][p][1] = (vy0 && vx1) ? wy0 * wx1 : 0.f;
        s_mi[t][p][2] = y1 * 64 + x0;  s_mw[t][p][2] = (vy1 && vx0) ? wy1 * wx0 : 0.f;
        s_mi[t][p][3] = y1 * 64 + x1;  s_mw[t][p][3] = (vy1 && vx1) ? wy1 * wx1 : 0.f;
    }
    __syncthreads();

    for (int j = wv; j < 54; j += 4) {
        const int t = j / 6, cb = cbq + j % 6;
        int   mi[4];
        float mw[4];
#pragma unroll
        for (int c = 0; c < 4; ++c) {
            mi[c] = s_mi[t][lmx][c];
            mw[c] = s_mw[t][lmx][c];
        }
        float a[8];
#pragma unroll
        for (int k = 0; k < 8; ++k) a[k] = 0.f;
#pragma unroll
        for (int c = 0; c < 4; ++c) {
            float wgt = mw[c];
            const short* src = xcat + (size_t)mi[c] * 1536 + 768 + cb * 32 + qd * 8;
            uint4 v = *(const uint4*)src;
            a[0] += wgt * bf2f(v.x & 0xffffu); a[1] += wgt * bf2f(v.x >> 16);
            a[2] += wgt * bf2f(v.y & 0xffffu); a[3] += wgt * bf2f(v.y >> 16);
            a[4] += wgt * bf2f(v.z & 0xffffu); a[5] += wgt * bf2f(v.z >> 16);
            a[6] += wgt * bf2f(v.w & 0xffffu); a[7] += wgt * bf2f(v.w >> 16);
        }
        uint4 o;
        o.x = f2bf(a[0]) | ((unsigned)f2bf(a[1]) << 16);
        o.y = f2bf(a[2]) | ((unsigned)f2bf(a[3]) << 16);
        o.z = f2bf(a[4]) | ((unsigned)f2bf(a[5]) << 16);
        o.w = f2bf(a[6]) | ((unsigned)f2bf(a[7]) << 16);
        size_t addr = ((((size_t)pg * 216 + cb * 9 + t) * 4 + ma) * 64 + lane) * 8;
        *(uint4*)&Smp[addr] = o;
    }
}

// ---------------------------------------------------------------------------
// Deform GEMM v4 (best verified, R8): LDS staging (3-slot, global_load_lds,
// counted vmcnt) + one-step-ahead LDS->reg prefetch: MFMA(step s) runs on
// registers loaded LAST step while this step's ds_reads fill the DS pipe.
// Unroll x2 with named reg sets A/B; slot rotation (cA,cB,cC)<-(cC,cA,cB).
// ---------------------------------------------------------------------------
__global__ __launch_bounds__(256, 3)
void dgemm_k(const short* __restrict__ Ap, const short* __restrict__ Bp,
             short* __restrict__ P)
{
    __shared__ __align__(16) short sL[3 * 8192];   // 3 slots x 16 KB

    const int tid = threadIdx.x, lane = tid & 63, wv = tid >> 6;
    const int lm = lane & 15, quad = lane >> 4;
    const int mg = blockIdx.y * 2 + (wv >> 1);    // 64-cout group 0..11
    const int pg = blockIdx.x * 2 + (wv & 1);     // 64-px group 0..63
    const int s0 = blockIdx.z * 54;

    // staging role: wave wv copies one 4KB chunk per s-step
    const short* stSrc;
    int stChunk;
    if (wv < 2) {
        stSrc = Ap + ((size_t)(blockIdx.y * 2 + wv) * 216 + s0) * 2048;
        stChunk = wv * 2048;
    } else {
        stSrc = Bp + ((size_t)(blockIdx.x * 2 + (wv - 2)) * 216 + s0) * 2048;
        stChunk = 4096 + (wv - 2) * 2048;
    }

    f4v acc[4][4];
#pragma unroll
    for (int ma = 0; ma < 4; ++ma)
#pragma unroll
        for (int nb = 0; nb < 4; ++nb)
#pragma unroll
            for (int r = 0; r < 4; ++r) acc[ma][nb][r] = 0.f;

    // prologue: stage s=0 -> slot0, s=1 -> slot1
#pragma unroll
    for (int j = 0; j < 4; ++j)
        GLDS16(stSrc + (size_t)0 * 2048 + j * 512 + lane * 8,
               &sL[0 * 8192 + stChunk + j * 512]);
#pragma unroll
    for (int j = 0; j < 4; ++j)
        GLDS16(stSrc + (size_t)1 * 2048 + j * 512 + lane * 8,
               &sL[1 * 8192 + stChunk + j * 512]);
    asm volatile("s_waitcnt vmcnt(4)" ::: "memory");   // stage(0) landed (own)
    __builtin_amdgcn_s_barrier();                      // ... by all waves
    __builtin_amdgcn_sched_barrier(0);

    const int aOff = (wv >> 1) * 2048;
    const int bOff = 4096 + (wv & 1) * 2048;

    s8v avA[4], bvA[4], avB[4], bvB[4];
    // read slot0 -> regs A (frags for step 0)
#pragma unroll
    for (int f = 0; f < 4; ++f) {
        avA[f] = *(const s8v*)&sL[0 * 8192 + aOff + f * 512 + lane * 8];
        bvA[f] = *(const s8v*)&sL[0 * 8192 + bOff + f * 512 + lane * 8];
    }

    int cA = 0, cB = 1, cC = 2;   // slots of steps s, s+1, s+2

    for (int s = 0; s < 52; s += 2) {
        // ---- even: execute step s, read step s+1, stage step s+2 ----
#pragma unroll
        for (int j = 0; j < 4; ++j)
            GLDS16(stSrc + (size_t)(s + 2) * 2048 + j * 512 + lane * 8,
                   &sL[cC * 8192 + stChunk + j * 512]);
        asm volatile("s_waitcnt vmcnt(4)" ::: "memory");   // stage(s+1) landed
        __builtin_amdgcn_s_barrier();
        __builtin_amdgcn_sched_barrier(0);
        {
            const int base = cB * 8192;
#pragma unroll
            for (int f = 0; f < 4; ++f) {
                avB[f] = *(const s8v*)&sL[base + aOff + f * 512 + lane * 8];
                bvB[f] = *(const s8v*)&sL[base + bOff + f * 512 + lane * 8];
            }
        }
#pragma unroll
        for (int ma = 0; ma < 4; ++ma)
#pragma unroll
            for (int nb = 0; nb < 4; ++nb)
                acc[ma][nb] = __builtin_amdgcn_mfma_f32_16x16x32_bf16(
                    avA[ma], bvA[nb], acc[ma][nb], 0, 0, 0);

        // ---- odd: execute step s+1, read step s+2, stage step s+3 ----
#pragma unroll
        for (int j = 0; j < 4; ++j)
            GLDS16(stSrc + (size_t)(s + 3) * 2048 + j * 512 + lane * 8,
                   &sL[cA * 8192 + stChunk + j * 512]);
        asm volatile("s_waitcnt vmcnt(4)" ::: "memory");   // stage(s+2) landed
        __builtin_amdgcn_s_barrier();
        __builtin_amdgcn_sched_barrier(0);
        {
            const int base = cC * 8192;
#pragma unroll
            for (int f = 0; f < 4; ++f) {
                avA[f] = *(const s8v*)&sL[base + aOff + f * 512 + lane * 8];
                bvA[f] = *(const s8v*)&sL[base + bOff + f * 512 + lane * 8];
            }
        }
#pragma unroll
        for (int ma = 0; ma < 4; ++ma)
#pragma unroll
            for (int nb = 0; nb < 4; ++nb)
                acc[ma][nb] = __builtin_amdgcn_mfma_f32_16x16x32_bf16(
                    avB[ma], bvB[nb], acc[ma][nb], 0, 0, 0);

        // rotate slots by two steps: (cA,cB,cC) <- (cC,cA,cB)
        int nA = cC, nB = cA, nC = cB;
        cA = nA; cB = nB; cC = nC;
    }

    // ---- tail: steps 52 (regs A, already loaded) and 53 ----
    asm volatile("s_waitcnt vmcnt(0)" ::: "memory");       // stage(53) landed
    __builtin_amdgcn_s_barrier();
    __builtin_amdgcn_sched_barrier(0);
    {
        const int base = cB * 8192;                        // slot of step 53
#pragma unroll
        for (int f = 0; f < 4; ++f) {
            avB[f] = *(const s8v*)&sL[base + aOff + f * 512 + lane * 8];
            bvB[f] = *(const s8v*)&sL[base + bOff + f * 512 + lane * 8];
        }
    }
#pragma unroll
    for (int ma = 0; ma < 4; ++ma)
#pragma unroll
        for (int nb = 0; nb < 4; ++nb)
            acc[ma][nb] = __builtin_amdgcn_mfma_f32_16x16x32_bf16(
                avA[ma], bvA[nb], acc[ma][nb], 0, 0, 0);
#pragma unroll
    for (int ma = 0; ma < 4; ++ma)
#pragma unroll
        for (int nb = 0; nb < 4; ++nb)
            acc[ma][nb] = __builtin_amdgcn_mfma_f32_16x16x32_bf16(
                avB[ma], bvB[nb], acc[ma][nb], 0, 0, 0);

    short* p = P + (size_t)blockIdx.z * 768 * HWPX;
#pragma unroll
    for (int ma = 0; ma < 4; ++ma)
#pragma unroll
        for (int nb = 0; nb < 4; ++nb)
#pragma unroll
            for (int r = 0; r < 4; ++r)
                p[(size_t)(mg * 64 + ma * 16 + quad * 4 + r) * HWPX
                  + pg * 64 + nb * 16 + lm] = (short)f2bf(acc[ma][nb][r]);
}

// out f32 = sum of 4 bf16 partials
__global__ __launch_bounds__(256)
void ep_dg_k(const short* __restrict__ P, float* __restrict__ out)
{
    int i = blockIdx.x * 256 + threadIdx.x;
    if (i >= 768 * HWPX / 8) return;
    size_t base = (size_t)i * 8;
    float s[8];
#pragma unroll
    for (int j = 0; j < 8; ++j) s[j] = 0.f;
    for (int sp = 0; sp < 4; ++sp) {
        uint4 v = *(const uint4*)&P[(size_t)sp * 768 * HWPX + base];
        s[0] += bf2f(v.x & 0xffffu); s[1] += bf2f(v.x >> 16);
        s[2] += bf2f(v.y & 0xffffu); s[3] += bf2f(v.y >> 16);
        s[4] += bf2f(v.z & 0xffffu); s[5] += bf2f(v.z >> 16);
        s[6] += bf2f(v.w & 0xffffu); s[7] += bf2f(v.w >> 16);
    }
    float4 o0 = make_float4(s[0], s[1], s[2], s[3]);
    float4 o1 = make_float4(s[4], s[5], s[6], s[7]);
    *(float4*)&out[base]     = o0;
    *(float4*)&out[base + 4] = o1;
}

// ---------------------------------------------------------------------------
extern "C" void kernel_launch(void* const* d_in, const int* in_sizes, int n_in,
                              void* d_out, int out_size, void* d_ws, size_t ws_size,
                              hipStream_t stream)
{
    const float* x_in  = (const float*)d_in[0];
    const float* x_ref = (const float*)d_in[1];
    const float* w1    = (const float*)d_in[2];
    const float* w2    = (const float*)d_in[3];
    const float* w3    = (const float*)d_in[4];
    const float* ow    = (const float*)d_in[5];
    const float* dw    = (const float*)d_in[6];
    float* out = (float*)d_out;

    char* w = (char*)d_ws;
    size_t off = 0;
    auto carve = [&](size_t bytes) {
        void* p = w + off;
        off += (bytes + 255) & ~(size_t)255;
        return p;
    };
    short* xcat = (short*)carve((size_t)4096 * 1536 * 2);        // 12.58 MB
    short* w1p  = (short*)carve((size_t)C1 * 2);                 //  5.31 MB (NB=4)
    short* w2p  = (short*)carve((size_t)(C2 - C1) * 2);          //  0.66 MB (NB=2)
    short* w3p  = (short*)carve((size_t)(C3 - C2) * 2);          //  5.31 MB (NB=4)
    short* w4p  = (short*)carve((size_t)(C4 - C3) * 2);          //  0.88 MB (NB=2)
    short* dwp  = (short*)carve((size_t)(C5 - C4) * 2);          // 10.62 MB (NB=4)
    float* offs = (float*)carve((size_t)18 * 4096 * 4);          //  0.29 MB
    short* Smp  = (short*)carve((size_t)4096 * 6912 * 2);        // 56.62 MB
    // REGION R: 25.17 MB, aliased across phases
    char*  R    = (char*)carve((size_t)2 * 768 * 4096 * 4);
    short* rh1  = (short*)R;                    // [4096][192] bf16
    short* rh2  = (short*)(R + 1572864);        // [4096][192] bf16
    short* p4   = (short*)(R + 3145728);        // conv4 partials [48][4096][32]
    short* Pcv  = Smp;                          // conv partials (Smp idle til sample)
    short* Pdg  = (short*)R;                    // dgemm partials [4][768][4096] bf16

    // prep: transpose/concat (1536 blocks) + wave-packed weights (618 blocks)
    prep_k<<<1536 + 618, 256, 0, stream>>>(
        x_in, x_ref, xcat, w1, w2, w3, ow, dw, w1p, w2p, w3p, w4p, dwp);

    const int n8 = 4096 * 192 / 8;
    // conv1: 1536->192 relu; N=64, ksplit 16 x 3 chunks; partials in Smp
    convf_k<4, false><<<dim3(16, 3, 16), 256, 0, stream>>>(
        xcat, nullptr, 1536, w1p, 432, 3, Pcv, 192, 4096 * 192);
    ep_sumb_k<<<(n8 + 255) / 256, 256, 0, stream>>>(Pcv, rh1, 16, (size_t)4096 * 192, n8, 1);
    // conv2: 192->192 relu; NB=2 (N=32) -> grid (16,6,6)=576 blocks, 2.25/CU
    convf_k<2, false><<<dim3(16, 6, 6), 256, 0, stream>>>(
        rh1, nullptr, 192, w2p, 54, 1, Pcv, 192, 4096 * 192);
    ep_sumb_k<<<(n8 + 255) / 256, 256, 0, stream>>>(Pcv, rh2, 6, (size_t)4096 * 192, n8, 1);
    // conv3: 192->1536; N=64, ksplit 2 x 3 chunks; partials stay in Smp
    convf_k<4, false><<<dim3(16, 24, 2), 256, 0, stream>>>(
        rh2, nullptr, 192, w3p, 54, 3, Pcv, 1536, 4096 * 1536);
    // conv4: 1536->18(pad 32); input = SUM of conv3's 2 partials (fused
    // epilogue during halo staging); partials -> p4 (R region, est slot)
    convf_k<2, true><<<dim3(16, 1, 48), 256, 0, stream>>>(
        Pcv, Pcv + (size_t)4096 * 1536, 1536, w4p, 432, 1, p4, 32, 4096 * 32);
    ep_offs_k<<<(18 * HWPX + 255) / 256, 256, 0, stream>>>(p4, offs, 48);
    // deformable conv: coalesced-write sampling, pipelined LDS-staged GEMM
    sample_k<<<dim3(256, 4), 256, 0, stream>>>(xcat, offs, Smp);
    dgemm_k<<<dim3(32, 6, 4), 256, 0, stream>>>(dwp, Smp, Pdg);
    ep_dg_k<<<(768 * HWPX / 8 + 255) / 256, 256, 0, stream>>>(Pdg, out);
}